// Round 1
// baseline (4286.571 us; speedup 1.0000x reference)
//
#include <hip/hip_runtime.h>
#include <cstdint>
#include <cstddef>

#define IN_F 128
#define HID  128
#define OUTF 64

static constexpr int TPB = 256;

// ---------- index dtype detection (int32 vs int64 layout) ----------
__global__ void detect_i64_kernel(const uint32_t* __restrict__ p, int npairs, int* __restrict__ flag) {
    __shared__ int anynz;
    if (threadIdx.x == 0) anynz = 0;
    __syncthreads();
    int i = threadIdx.x;
    if (i < npairs && p[2 * i + 1] != 0u) atomicOr(&anynz, 1);
    __syncthreads();
    // all high-dwords zero over 256 samples => int64 layout
    if (threadIdx.x == 0) *flag = (anynz == 0) ? 1 : 0;
}

__global__ void convert_idx_kernel(const void* __restrict__ p, int* __restrict__ out, int n,
                                   const int* __restrict__ flag) {
    int i = blockIdx.x * TPB + threadIdx.x;
    if (i >= n) return;
    if (*flag) out[i] = (int)((const long long*)p)[i];
    else       out[i] = ((const int*)p)[i];
}

// ---------- degree / normalization ----------
__global__ void deg_init_kernel(float* __restrict__ deg, int n) {
    int i = blockIdx.x * TPB + threadIdx.x;
    if (i < n) deg[i] = 1.0f;  // self-loop
}

__global__ void deg_accum_kernel(const int* __restrict__ dst, float* __restrict__ deg, int nE) {
    int i = blockIdx.x * TPB + threadIdx.x;
    if (i < nE) unsafeAtomicAdd(&deg[dst[i]], 1.0f);
}

__global__ void rsqrt_kernel(float* __restrict__ deg, int n) {
    int i = blockIdx.x * TPB + threadIdx.x;
    if (i < n) deg[i] = rsqrtf(fmaxf(deg[i], 1.0f));
}

// ---------- GEMM: out[r][:] = (X[r][:] @ W) * dis[r]   (K=128 fixed) ----------
template <int C>
__global__ __launch_bounds__(256) void gemm_dis_kernel(
    const float* __restrict__ X, const float* __restrict__ W,
    const float* __restrict__ dis, float* __restrict__ out, int nrows)
{
    constexpr int K    = 128;
    constexpr int TX   = C / 4;        // threads along cols (each owns 4 contiguous cols)
    constexpr int TY   = 256 / TX;     // 8 (C=128) or 16 (C=64)
    constexpr int ROWS = TY * 4;       // 32 or 64 rows per block
    constexpr int XPAD = (C == 64) ? 1 : 0;  // pad to break 4-way bank conflict at TY=16

    __shared__ float4 Wlds[K][TX];             // 64KB / 32KB
    __shared__ float4 Xlds[ROWS][K / 4 + XPAD];

    int rowBase = blockIdx.x * ROWS;
    int nr = min(ROWS, nrows - rowBase);

    for (int i = threadIdx.x; i < K * TX; i += 256)
        ((float4*)Wlds)[i] = ((const float4*)W)[i];
    for (int i = threadIdx.x; i < nr * (K / 4); i += 256) {
        int r = i >> 5, kq = i & 31;  // K/4 == 32
        Xlds[r][kq] = ((const float4*)(X + (size_t)(rowBase + r) * K))[kq];
    }
    __syncthreads();

    int tx = threadIdx.x % TX, ty = threadIdx.x / TX;
    float acc[4][4] = {};
    for (int kq = 0; kq < K / 4; ++kq) {
        float4 w0 = Wlds[4 * kq + 0][tx];
        float4 w1 = Wlds[4 * kq + 1][tx];
        float4 w2 = Wlds[4 * kq + 2][tx];
        float4 w3 = Wlds[4 * kq + 3][tx];
#pragma unroll
        for (int i2 = 0; i2 < 4; ++i2) {
            float4 xv = Xlds[ty * 4 + i2][kq];
            acc[i2][0] += xv.x * w0.x + xv.y * w1.x + xv.z * w2.x + xv.w * w3.x;
            acc[i2][1] += xv.x * w0.y + xv.y * w1.y + xv.z * w2.y + xv.w * w3.y;
            acc[i2][2] += xv.x * w0.z + xv.y * w1.z + xv.z * w2.z + xv.w * w3.z;
            acc[i2][3] += xv.x * w0.w + xv.y * w1.w + xv.z * w2.w + xv.w * w3.w;
        }
    }
#pragma unroll
    for (int i2 = 0; i2 < 4; ++i2) {
        int r = rowBase + ty * 4 + i2;
        if (r < nrows) {
            float dsc = dis[r];
            float4 o;
            o.x = acc[i2][0] * dsc; o.y = acc[i2][1] * dsc;
            o.z = acc[i2][2] * dsc; o.w = acc[i2][3] * dsc;
            ((float4*)(out + (size_t)r * C))[tx] = o;
        }
    }
}

// ---------- agg init (self-loop term): agg = hs ----------
__global__ void copy4_kernel(const float4* __restrict__ src, float4* __restrict__ dst, int n4) {
    int i = blockIdx.x * TPB + threadIdx.x;
    if (i < n4) dst[i] = src[i];
}

// ---------- edge scatter: agg[dst] += hs[src] ----------
template <int C>
__global__ __launch_bounds__(256) void scatter_add_kernel(
    const float* __restrict__ hs, const int* __restrict__ src, const int* __restrict__ dst,
    float* __restrict__ agg, int nE)
{
    constexpr int Q = C / 4;
    int gid = blockIdx.x * TPB + threadIdx.x;
    if (gid >= nE * Q) return;
    int e = gid / Q;
    int q = gid % Q;
    int s = src[e], d = dst[e];
    float4 v = ((const float4*)(hs + (size_t)s * C))[q];
    float* a = agg + (size_t)d * C + 4 * q;
    unsafeAtomicAdd(a + 0, v.x);
    unsafeAtomicAdd(a + 1, v.y);
    unsafeAtomicAdd(a + 2, v.z);
    unsafeAtomicAdd(a + 3, v.w);
}

// ---------- epilogues ----------
template <int Q>
__global__ void bias_relu_kernel(const float* __restrict__ agg, const float* __restrict__ dis,
                                 const float* __restrict__ b, float* __restrict__ out, int n4) {
    int i = blockIdx.x * TPB + threadIdx.x;
    if (i >= n4) return;
    int r = i / Q, q = i % Q;
    float dsc = dis[r];
    float4 v  = ((const float4*)agg)[i];
    float4 bb = ((const float4*)b)[q];
    float4 o;
    o.x = fmaxf(v.x * dsc + bb.x, 0.0f);
    o.y = fmaxf(v.y * dsc + bb.y, 0.0f);
    o.z = fmaxf(v.z * dsc + bb.z, 0.0f);
    o.w = fmaxf(v.w * dsc + bb.w, 0.0f);
    ((float4*)out)[i] = o;
}

template <int Q>
__global__ void bias_sigmoid_kernel(const float* __restrict__ agg, const float* __restrict__ dis,
                                    const float* __restrict__ b, float* __restrict__ out, int n4) {
    int i = blockIdx.x * TPB + threadIdx.x;
    if (i >= n4) return;
    int r = i / Q, q = i % Q;
    float dsc = dis[r];
    float4 v  = ((const float4*)agg)[i];
    float4 bb = ((const float4*)b)[q];
    float4 o;
    o.x = 0.1f + 0.8f / (1.0f + __expf(-(v.x * dsc + bb.x)));
    o.y = 0.1f + 0.8f / (1.0f + __expf(-(v.y * dsc + bb.y)));
    o.z = 0.1f + 0.8f / (1.0f + __expf(-(v.z * dsc + bb.z)));
    o.w = 0.1f + 0.8f / (1.0f + __expf(-(v.w * dsc + bb.w)));
    ((float4*)out)[i] = o;
}

extern "C" void kernel_launch(void* const* d_in, const int* in_sizes, int n_in,
                              void* d_out, int out_size, void* d_ws, size_t ws_size,
                              hipStream_t stream) {
    const float* x  = (const float*)d_in[0];
    const void*  ei = d_in[1];
    const float* W1 = (const float*)d_in[2];
    const float* b1 = (const float*)d_in[3];
    const float* W2 = (const float*)d_in[4];
    const float* b2 = (const float*)d_in[5];

    const int N = in_sizes[0] / IN_F;   // 100000
    const int E = in_sizes[1] / 2;      // 1600000

    auto alignup = [](size_t v) { return (v + 255) & ~(size_t)255; };
    char* w = (char*)d_ws;
    size_t off = 0;
    int*   flag  = (int*)(w + off);   off = alignup(off + 16);
    int*   idx32 = (int*)(w + off);   off = alignup(off + (size_t)2 * E * sizeof(int));
    float* dis   = (float*)(w + off); off = alignup(off + (size_t)N * sizeof(float));
    float* B1    = (float*)(w + off); off = alignup(off + (size_t)N * HID * sizeof(float));
    float* B2    = (float*)(w + off); off = alignup(off + (size_t)N * HID * sizeof(float));
    // total ~115.6 MB of d_ws used; hs2 lives in d_out (N*64)

    const int* srcI = idx32;
    const int* dstI = idx32 + E;
    float* hs2 = (float*)d_out;

    // indices
    detect_i64_kernel<<<1, TPB, 0, stream>>>((const uint32_t*)ei, 256, flag);
    convert_idx_kernel<<<(2 * E + TPB - 1) / TPB, TPB, 0, stream>>>(ei, idx32, 2 * E, flag);

    // degree -> dis
    deg_init_kernel<<<(N + TPB - 1) / TPB, TPB, 0, stream>>>(dis, N);
    deg_accum_kernel<<<(E + TPB - 1) / TPB, TPB, 0, stream>>>(dstI, dis, E);
    rsqrt_kernel<<<(N + TPB - 1) / TPB, TPB, 0, stream>>>(dis, N);

    // ---- layer 1: hs1 = (x@W1)*dis ; agg = hs1 + scatter ; h1 = relu(dis*agg + b1)
    gemm_dis_kernel<HID><<<(N + 31) / 32, TPB, 0, stream>>>(x, W1, dis, B1, N);
    copy4_kernel<<<(N * (HID / 4) + TPB - 1) / TPB, TPB, 0, stream>>>((const float4*)B1, (float4*)B2, N * (HID / 4));
    scatter_add_kernel<HID><<<(unsigned)((E * (HID / 4) + TPB - 1) / TPB), TPB, 0, stream>>>(B1, srcI, dstI, B2, E);
    bias_relu_kernel<HID / 4><<<(N * (HID / 4) + TPB - 1) / TPB, TPB, 0, stream>>>(B2, dis, b1, B1, N * (HID / 4));

    // ---- layer 2: hs2 = (h1@W2)*dis ; agg = hs2 + scatter ; out = 0.1 + 0.8*sigmoid(dis*agg + b2)
    gemm_dis_kernel<OUTF><<<(N + 63) / 64, TPB, 0, stream>>>(B1, W2, dis, hs2, N);
    copy4_kernel<<<(N * (OUTF / 4) + TPB - 1) / TPB, TPB, 0, stream>>>((const float4*)hs2, (float4*)B2, N * (OUTF / 4));
    scatter_add_kernel<OUTF><<<(unsigned)((E * (OUTF / 4) + TPB - 1) / TPB), TPB, 0, stream>>>(hs2, srcI, dstI, B2, E);
    bias_sigmoid_kernel<OUTF / 4><<<(N * (OUTF / 4) + TPB - 1) / TPB, TPB, 0, stream>>>(B2, dis, b2, (float*)d_out, N * (OUTF / 4));
}

// Round 3
// 502.608 us; speedup vs baseline: 8.5287x; 8.5287x over previous
//
#include <hip/hip_runtime.h>
#include <cstdint>
#include <cstddef>

#define IN_F 128
#define HID  128
#define OUTF 64

static constexpr int TPB = 256;

// ---------- index dtype detection (int32 vs int64 layout) ----------
__global__ void detect_i64_kernel(const uint32_t* __restrict__ p, int npairs, int* __restrict__ flag) {
    __shared__ int anynz;
    if (threadIdx.x == 0) anynz = 0;
    __syncthreads();
    int i = threadIdx.x;
    if (i < npairs && p[2 * i + 1] != 0u) atomicOr(&anynz, 1);
    __syncthreads();
    // all high-dwords zero over 256 samples => int64 layout
    if (threadIdx.x == 0) *flag = (anynz == 0) ? 1 : 0;
}

__device__ __forceinline__ int load_idx(const void* p, int i, bool i64) {
    return i64 ? (int)((const long long*)p)[i] : ((const int*)p)[i];
}

// ---------- zero ints ----------
__global__ void zero_int_kernel(int* __restrict__ p, int n) {
    int i = blockIdx.x * TPB + threadIdx.x;
    if (i < n) p[i] = 0;
}

// ---------- in-degree histogram (edges only; self-loop added later) ----------
__global__ void hist_kernel(const void* __restrict__ ei, int E, const int* __restrict__ flag,
                            int* __restrict__ counts) {
    int e = blockIdx.x * TPB + threadIdx.x;
    if (e >= E) return;
    bool i64 = (*flag != 0);
    int d = load_idx(ei, E + e, i64);   // dst row
    atomicAdd(&counts[d], 1);
}

// ---------- dis = rsqrt(deg), deg = counts + 1 (self-loop) ----------
__global__ void dis_kernel(const int* __restrict__ counts, float* __restrict__ dis, int n) {
    int i = blockIdx.x * TPB + threadIdx.x;
    if (i < n) dis[i] = rsqrtf((float)(counts[i] + 1));
}

// ---------- 3-phase exclusive scan over counts -> row_ptr ----------
__global__ void scan_block_kernel(const int* __restrict__ counts, int* __restrict__ excl,
                                  int* __restrict__ partials, int n) {
    __shared__ int tmp[TPB];
    int tid = threadIdx.x, gid = blockIdx.x * TPB + tid;
    int v = (gid < n) ? counts[gid] : 0;
    tmp[tid] = v;
    __syncthreads();
    for (int off = 1; off < TPB; off <<= 1) {
        int t = (tid >= off) ? tmp[tid - off] : 0;
        __syncthreads();
        tmp[tid] += t;
        __syncthreads();
    }
    if (gid < n) excl[gid] = tmp[tid] - v;
    if (tid == TPB - 1) partials[blockIdx.x] = tmp[TPB - 1];
}

__global__ void scan_partials_kernel(int* __restrict__ partials, int nb) {
    __shared__ int tmp[512];
    int tid = threadIdx.x;
    int v = (tid < nb) ? partials[tid] : 0;
    tmp[tid] = v;
    __syncthreads();
    for (int off = 1; off < 512; off <<= 1) {
        int t = (tid >= off) ? tmp[tid - off] : 0;
        __syncthreads();
        tmp[tid] += t;
        __syncthreads();
    }
    if (tid < nb) partials[tid] = tmp[tid] - v;  // exclusive
}

__global__ void add_offsets_kernel(int* __restrict__ excl, const int* __restrict__ partials, int n) {
    int i = blockIdx.x * TPB + threadIdx.x;
    if (i < n) excl[i] += partials[blockIdx.x];
}

// ---------- CSR fill: csr_src[row_ptr[d] + cursor[d]++] = s ----------
__global__ void fill_kernel(const void* __restrict__ ei, int E, const int* __restrict__ flag,
                            const int* __restrict__ row_ptr, int* __restrict__ cursor,
                            int* __restrict__ csr_src) {
    int e = blockIdx.x * TPB + threadIdx.x;
    if (e >= E) return;
    bool i64 = (*flag != 0);
    int s = load_idx(ei, e, i64);
    int d = load_idx(ei, E + e, i64);
    int pos = row_ptr[d] + atomicAdd(&cursor[d], 1);
    csr_src[pos] = s;
}

// ---------- GEMM: out[r][:] = (X[r][:] @ W) * dis[r]   (K=128 fixed) ----------
template <int C>
__global__ __launch_bounds__(256) void gemm_dis_kernel(
    const float* __restrict__ X, const float* __restrict__ W,
    const float* __restrict__ dis, float* __restrict__ out, int nrows)
{
    constexpr int K    = 128;
    constexpr int TX   = C / 4;
    constexpr int TY   = 256 / TX;
    constexpr int ROWS = TY * 4;
    constexpr int XPAD = (C == 64) ? 1 : 0;

    __shared__ float4 Wlds[K][TX];
    __shared__ float4 Xlds[ROWS][K / 4 + XPAD];

    int rowBase = blockIdx.x * ROWS;
    int nr = min(ROWS, nrows - rowBase);

    for (int i = threadIdx.x; i < K * TX; i += 256)
        ((float4*)Wlds)[i] = ((const float4*)W)[i];
    for (int i = threadIdx.x; i < nr * (K / 4); i += 256) {
        int r = i >> 5, kq = i & 31;  // K/4 == 32
        Xlds[r][kq] = ((const float4*)(X + (size_t)(rowBase + r) * K))[kq];
    }
    __syncthreads();

    int tx = threadIdx.x % TX, ty = threadIdx.x / TX;
    float acc[4][4] = {};
    for (int kq = 0; kq < K / 4; ++kq) {
        float4 w0 = Wlds[4 * kq + 0][tx];
        float4 w1 = Wlds[4 * kq + 1][tx];
        float4 w2 = Wlds[4 * kq + 2][tx];
        float4 w3 = Wlds[4 * kq + 3][tx];
#pragma unroll
        for (int i2 = 0; i2 < 4; ++i2) {
            float4 xv = Xlds[ty * 4 + i2][kq];
            acc[i2][0] += xv.x * w0.x + xv.y * w1.x + xv.z * w2.x + xv.w * w3.x;
            acc[i2][1] += xv.x * w0.y + xv.y * w1.y + xv.z * w2.y + xv.w * w3.y;
            acc[i2][2] += xv.x * w0.z + xv.y * w1.z + xv.z * w2.z + xv.w * w3.z;
            acc[i2][3] += xv.x * w0.w + xv.y * w1.w + xv.z * w2.w + xv.w * w3.w;
        }
    }
#pragma unroll
    for (int i2 = 0; i2 < 4; ++i2) {
        int r = rowBase + ty * 4 + i2;
        if (r < nrows) {
            float dsc = dis[r];
            float4 o;
            o.x = acc[i2][0] * dsc; o.y = acc[i2][1] * dsc;
            o.z = acc[i2][2] * dsc; o.w = acc[i2][3] * dsc;
            ((float4*)(out + (size_t)r * C))[tx] = o;
        }
    }
}

// ---------- gather-side aggregation, fused epilogue ----------
// out[node] = act( dis[node] * (hs[node] + sum_{s in csr[node]} hs[s]) + b )
// ACT: 0 = relu, 1 = 0.1 + 0.8*sigmoid
template <int C, int ACT>
__global__ __launch_bounds__(256) void agg_kernel(
    const float* __restrict__ hs, const int* __restrict__ csr,
    const int* __restrict__ row_ptr, const int* __restrict__ counts,
    const float* __restrict__ dis, const float* __restrict__ b,
    float* __restrict__ out, int n)
{
    constexpr int V = C / 64;  // floats per lane: 2 (C=128) or 1 (C=64)
    int wave = threadIdx.x >> 6;
    int lane = threadIdx.x & 63;
    int node = blockIdx.x * 4 + wave;
    if (node >= n) return;

    float acc[V];
    {   // self-loop init
        const float* row = hs + (size_t)node * C + lane * V;
#pragma unroll
        for (int j = 0; j < V; ++j) acc[j] = row[j];
    }

    int start = row_ptr[node];
    int end   = start + counts[node];
    int k = start;
    for (; k + 1 < end; k += 2) {   // unroll 2 for ILP
        int s0 = csr[k], s1 = csr[k + 1];
        const float* r0 = hs + (size_t)s0 * C + lane * V;
        const float* r1 = hs + (size_t)s1 * C + lane * V;
        float t0[V], t1[V];
#pragma unroll
        for (int j = 0; j < V; ++j) t0[j] = r0[j];
#pragma unroll
        for (int j = 0; j < V; ++j) t1[j] = r1[j];
#pragma unroll
        for (int j = 0; j < V; ++j) acc[j] += t0[j] + t1[j];
    }
    if (k < end) {
        int s0 = csr[k];
        const float* r0 = hs + (size_t)s0 * C + lane * V;
#pragma unroll
        for (int j = 0; j < V; ++j) acc[j] += r0[j];
    }

    float dsc = dis[node];
    float* o = out + (size_t)node * C + lane * V;
#pragma unroll
    for (int j = 0; j < V; ++j) {
        float v = acc[j] * dsc + b[lane * V + j];
        if (ACT == 0) v = fmaxf(v, 0.0f);
        else          v = 0.1f + 0.8f / (1.0f + __expf(-v));
        o[j] = v;
    }
}

extern "C" void kernel_launch(void* const* d_in, const int* in_sizes, int n_in,
                              void* d_out, int out_size, void* d_ws, size_t ws_size,
                              hipStream_t stream) {
    const float* x  = (const float*)d_in[0];
    const void*  ei = d_in[1];
    const float* W1 = (const float*)d_in[2];
    const float* b1 = (const float*)d_in[3];
    const float* W2 = (const float*)d_in[4];
    const float* b2 = (const float*)d_in[5];

    const int N = in_sizes[0] / IN_F;   // 100000
    const int E = in_sizes[1] / 2;      // 1600000

    auto alignup = [](size_t v) { return (v + 255) & ~(size_t)255; };
    char* w = (char*)d_ws;
    size_t off = 0;
    int*   flag     = (int*)(w + off);   off = alignup(off + 16);
    // counts and cursor MUST be one contiguous block: cursor = counts + N,
    // zeroed together as 2N ints. (R2 crash: alignup padding between separate
    // allocations left the last 32 cursor entries poisoned -> wild CSR writes.)
    int*   counts   = (int*)(w + off);   off = alignup(off + (size_t)2 * N * sizeof(int));
    int*   cursor   = counts + N;
    int*   row_ptr  = (int*)(w + off);   off = alignup(off + (size_t)N * sizeof(int));
    int*   partials = (int*)(w + off);   off = alignup(off + 512 * sizeof(int));
    float* dis      = (float*)(w + off); off = alignup(off + (size_t)N * sizeof(float));
    int*   csr      = (int*)(w + off);   off = alignup(off + (size_t)E * sizeof(int));
    float* A        = (float*)(w + off); off = alignup(off + (size_t)N * HID * sizeof(float));
    float* B        = (float*)(w + off); off = alignup(off + (size_t)N * HID * sizeof(float));
    // total ~= 111 MB (round 1 used 115.6 MB successfully)

    const int nbN = (N + TPB - 1) / TPB;   // 391
    const int nbE = (E + TPB - 1) / TPB;

    // ---- index layout + degree + CSR build
    detect_i64_kernel<<<1, TPB, 0, stream>>>((const uint32_t*)ei, 256, flag);
    zero_int_kernel<<<(2 * N + TPB - 1) / TPB, TPB, 0, stream>>>(counts, 2 * N);
    hist_kernel<<<nbE, TPB, 0, stream>>>(ei, E, flag, counts);
    dis_kernel<<<nbN, TPB, 0, stream>>>(counts, dis, N);
    scan_block_kernel<<<nbN, TPB, 0, stream>>>(counts, row_ptr, partials, N);
    scan_partials_kernel<<<1, 512, 0, stream>>>(partials, nbN);
    add_offsets_kernel<<<nbN, TPB, 0, stream>>>(row_ptr, partials, N);
    fill_kernel<<<nbE, TPB, 0, stream>>>(ei, E, flag, row_ptr, cursor, csr);

    // ---- layer 1: hs1 = (x@W1)*dis ; h1 = relu(dis*(hs1[d] + sum hs1[s]) + b1)
    gemm_dis_kernel<HID><<<(N + 31) / 32, TPB, 0, stream>>>(x, W1, dis, A, N);
    agg_kernel<HID, 0><<<(N + 3) / 4, TPB, 0, stream>>>(A, csr, row_ptr, counts, dis, b1, B, N);

    // ---- layer 2: hs2 = (h1@W2)*dis ; out = 0.1+0.8*sigmoid(dis*(hs2[d]+sum hs2[s]) + b2)
    gemm_dis_kernel<OUTF><<<(N + 63) / 64, TPB, 0, stream>>>(B, W2, dis, A, N);
    agg_kernel<OUTF, 1><<<(N + 3) / 4, TPB, 0, stream>>>(A, csr, row_ptr, counts, dis, b2, (float*)d_out, N);
}

// Round 4
// 477.429 us; speedup vs baseline: 8.9785x; 1.0527x over previous
//
#include <hip/hip_runtime.h>
#include <cstdint>
#include <cstddef>

#define IN_F 128
#define HID  128
#define OUTF 64

typedef unsigned int  uint32;
typedef unsigned short ushort16;

static constexpr int TPB = 256;

// ---------- bf16 helpers (RNE) ----------
__device__ __forceinline__ float bf2f(ushort16 u) {
    return __uint_as_float(((uint32)u) << 16);
}
__device__ __forceinline__ ushort16 f2bf(float f) {
    uint32 x = __float_as_uint(f);
    x = (x + 0x7FFFu + ((x >> 16) & 1u)) >> 16;
    return (ushort16)x;
}
__device__ __forceinline__ uint32 packbf(float a, float b) {
    return (uint32)f2bf(a) | ((uint32)f2bf(b) << 16);
}

// ---------- index dtype detection (int32 vs int64 layout) ----------
__global__ void detect_i64_kernel(const uint32* __restrict__ p, int npairs, int* __restrict__ flag) {
    __shared__ int anynz;
    if (threadIdx.x == 0) anynz = 0;
    __syncthreads();
    int i = threadIdx.x;
    if (i < npairs && p[2 * i + 1] != 0u) atomicOr(&anynz, 1);
    __syncthreads();
    if (threadIdx.x == 0) *flag = (anynz == 0) ? 1 : 0;
}

__device__ __forceinline__ int load_idx(const void* p, int i, bool i64) {
    return i64 ? (int)((const long long*)p)[i] : ((const int*)p)[i];
}

// ---------- zero ints ----------
__global__ void zero_int_kernel(int* __restrict__ p, int n) {
    int i = blockIdx.x * TPB + threadIdx.x;
    if (i < n) p[i] = 0;
}

// ---------- in-degree histogram (edges only; self-loop added later) ----------
__global__ void hist_kernel(const void* __restrict__ ei, int E, const int* __restrict__ flag,
                            int* __restrict__ counts) {
    int e = blockIdx.x * TPB + threadIdx.x;
    if (e >= E) return;
    bool i64 = (*flag != 0);
    int d = load_idx(ei, E + e, i64);
    atomicAdd(&counts[d], 1);
}

// ---------- dis = rsqrt(deg), deg = counts + 1 (self-loop) ----------
__global__ void dis_kernel(const int* __restrict__ counts, float* __restrict__ dis, int n) {
    int i = blockIdx.x * TPB + threadIdx.x;
    if (i < n) dis[i] = rsqrtf((float)(counts[i] + 1));
}

// ---------- 3-phase exclusive scan over counts -> row_ptr ----------
__global__ void scan_block_kernel(const int* __restrict__ counts, int* __restrict__ excl,
                                  int* __restrict__ partials, int n) {
    __shared__ int tmp[TPB];
    int tid = threadIdx.x, gid = blockIdx.x * TPB + tid;
    int v = (gid < n) ? counts[gid] : 0;
    tmp[tid] = v;
    __syncthreads();
    for (int off = 1; off < TPB; off <<= 1) {
        int t = (tid >= off) ? tmp[tid - off] : 0;
        __syncthreads();
        tmp[tid] += t;
        __syncthreads();
    }
    if (gid < n) excl[gid] = tmp[tid] - v;
    if (tid == TPB - 1) partials[blockIdx.x] = tmp[TPB - 1];
}

__global__ void scan_partials_kernel(int* __restrict__ partials, int nb) {
    __shared__ int tmp[512];
    int tid = threadIdx.x;
    int v = (tid < nb) ? partials[tid] : 0;
    tmp[tid] = v;
    __syncthreads();
    for (int off = 1; off < 512; off <<= 1) {
        int t = (tid >= off) ? tmp[tid - off] : 0;
        __syncthreads();
        tmp[tid] += t;
        __syncthreads();
    }
    if (tid < nb) partials[tid] = tmp[tid] - v;  // exclusive
}

// writes BOTH row_ptr and cursor (cursor starts == row_ptr; fill bumps it)
__global__ void add_offsets_kernel(int* __restrict__ excl, const int* __restrict__ partials,
                                   int* __restrict__ cursor, int n) {
    int i = blockIdx.x * TPB + threadIdx.x;
    if (i < n) {
        int v = excl[i] + partials[blockIdx.x];
        excl[i] = v;
        cursor[i] = v;
    }
}

// ---------- CSR fill: csr[cursor[d]++] = s ----------
__global__ void fill_kernel(const void* __restrict__ ei, int E, const int* __restrict__ flag,
                            int* __restrict__ cursor, int* __restrict__ csr_src) {
    int e = blockIdx.x * TPB + threadIdx.x;
    if (e >= E) return;
    bool i64 = (*flag != 0);
    int s = load_idx(ei, e, i64);
    int d = load_idx(ei, E + e, i64);
    int pos = atomicAdd(&cursor[d], 1);
    csr_src[pos] = s;
}

// ---------- GEMM: out[r][:] = bf16( (X[r][:] @ W) * dis[r] )   (K=128 fixed) ----------
// XBF: X is bf16 (ushort), else fp32. Output always bf16.
template <int C, bool XBF>
__global__ __launch_bounds__(256) void gemm_dis_kernel(
    const void* __restrict__ Xv, const float* __restrict__ W,
    const float* __restrict__ dis, ushort16* __restrict__ out, int nrows)
{
    constexpr int K    = 128;
    constexpr int TX   = C / 4;        // 32 (C=128) or 16 (C=64)
    constexpr int TY   = 256 / TX;
    constexpr int ROWS = TY * 4;       // 32 or 64
    constexpr int XPAD = (C == 64) ? 1 : 0;

    __shared__ float4 Wlds[K][TX];
    __shared__ float4 Xlds[ROWS][K / 4 + XPAD];

    int rowBase = blockIdx.x * ROWS;
    int nr = min(ROWS, nrows - rowBase);

    for (int i = threadIdx.x; i < K * TX; i += 256)
        ((float4*)Wlds)[i] = ((const float4*)W)[i];
    for (int i = threadIdx.x; i < nr * (K / 4); i += 256) {
        int r = i >> 5, kq = i & 31;  // K/4 == 32
        if (XBF) {
            const ushort16* Xb = (const ushort16*)Xv;
            uint2 u = ((const uint2*)(Xb + (size_t)(rowBase + r) * K))[kq];
            float4 f;
            f.x = bf2f((ushort16)(u.x & 0xFFFF)); f.y = bf2f((ushort16)(u.x >> 16));
            f.z = bf2f((ushort16)(u.y & 0xFFFF)); f.w = bf2f((ushort16)(u.y >> 16));
            Xlds[r][kq] = f;
        } else {
            const float* Xf = (const float*)Xv;
            Xlds[r][kq] = ((const float4*)(Xf + (size_t)(rowBase + r) * K))[kq];
        }
    }
    __syncthreads();

    int tx = threadIdx.x % TX, ty = threadIdx.x / TX;
    float acc[4][4] = {};
    for (int kq = 0; kq < K / 4; ++kq) {
        float4 w0 = Wlds[4 * kq + 0][tx];
        float4 w1 = Wlds[4 * kq + 1][tx];
        float4 w2 = Wlds[4 * kq + 2][tx];
        float4 w3 = Wlds[4 * kq + 3][tx];
#pragma unroll
        for (int i2 = 0; i2 < 4; ++i2) {
            float4 xv = Xlds[ty * 4 + i2][kq];
            acc[i2][0] += xv.x * w0.x + xv.y * w1.x + xv.z * w2.x + xv.w * w3.x;
            acc[i2][1] += xv.x * w0.y + xv.y * w1.y + xv.z * w2.y + xv.w * w3.y;
            acc[i2][2] += xv.x * w0.z + xv.y * w1.z + xv.z * w2.z + xv.w * w3.z;
            acc[i2][3] += xv.x * w0.w + xv.y * w1.w + xv.z * w2.w + xv.w * w3.w;
        }
    }
#pragma unroll
    for (int i2 = 0; i2 < 4; ++i2) {
        int r = rowBase + ty * 4 + i2;
        if (r < nrows) {
            float dsc = dis[r];
            uint2 o;
            o.x = packbf(acc[i2][0] * dsc, acc[i2][1] * dsc);
            o.y = packbf(acc[i2][2] * dsc, acc[i2][3] * dsc);
            ((uint2*)(out + (size_t)r * C))[tx] = o;
        }
    }
}

// ---------- aggregation C=128: one wave per node, bf16 in, bf16 out (relu+bias) ----------
__global__ __launch_bounds__(256) void agg128_kernel(
    const ushort16* __restrict__ hs, const int* __restrict__ csr,
    const int* __restrict__ row_ptr, const int* __restrict__ counts,
    const float* __restrict__ dis, const float* __restrict__ b,
    ushort16* __restrict__ out, int n)
{
    int wave = threadIdx.x >> 6;
    int lane = threadIdx.x & 63;
    int node = blockIdx.x * 4 + wave;
    if (node >= n) return;

    float a0, a1;
    {
        uint32 u = ((const uint32*)(hs + (size_t)node * 128))[lane];
        a0 = bf2f((ushort16)(u & 0xFFFF));
        a1 = bf2f((ushort16)(u >> 16));
    }

    int start = row_ptr[node];
    int end   = start + counts[node];
    int k = start;
    for (; k + 1 < end; k += 2) {
        int s0 = csr[k], s1 = csr[k + 1];
        uint32 u0 = ((const uint32*)(hs + (size_t)s0 * 128))[lane];
        uint32 u1 = ((const uint32*)(hs + (size_t)s1 * 128))[lane];
        a0 += bf2f((ushort16)(u0 & 0xFFFF)) + bf2f((ushort16)(u1 & 0xFFFF));
        a1 += bf2f((ushort16)(u0 >> 16))    + bf2f((ushort16)(u1 >> 16));
    }
    if (k < end) {
        uint32 u0 = ((const uint32*)(hs + (size_t)csr[k] * 128))[lane];
        a0 += bf2f((ushort16)(u0 & 0xFFFF));
        a1 += bf2f((ushort16)(u0 >> 16));
    }

    float dsc = dis[node];
    float2 bb = ((const float2*)b)[lane];
    float v0 = fmaxf(a0 * dsc + bb.x, 0.0f);
    float v1 = fmaxf(a1 * dsc + bb.y, 0.0f);
    ((uint32*)(out + (size_t)node * 128))[lane] = packbf(v0, v1);
}

// ---------- aggregation C=64: one wave per node, 2 edges/iter (half-wave each), ----------
// ---------- bf16 in, fp32 out with sigmoid epilogue                             ----------
__global__ __launch_bounds__(256) void agg64_kernel(
    const ushort16* __restrict__ hs, const int* __restrict__ csr,
    const int* __restrict__ row_ptr, const int* __restrict__ counts,
    const float* __restrict__ dis, const float* __restrict__ b,
    float* __restrict__ out, int n)
{
    int wave = threadIdx.x >> 6;
    int lane = threadIdx.x & 63;
    int half = lane >> 5;        // 0 or 1
    int l    = lane & 31;
    int node = blockIdx.x * 4 + wave;
    if (node >= n) return;

    float a0 = 0.0f, a1 = 0.0f;
    if (half == 0) {   // self-loop in half 0
        uint32 u = ((const uint32*)(hs + (size_t)node * 64))[l];
        a0 = bf2f((ushort16)(u & 0xFFFF));
        a1 = bf2f((ushort16)(u >> 16));
    }

    int start = row_ptr[node];
    int end   = start + counts[node];
    int k = start;
    for (; k + 3 < end; k += 4) {   // 4 edges per iter: halves take k+half, k+2+half
        int s0 = csr[k + half];
        int s1 = csr[k + 2 + half];
        uint32 u0 = ((const uint32*)(hs + (size_t)s0 * 64))[l];
        uint32 u1 = ((const uint32*)(hs + (size_t)s1 * 64))[l];
        a0 += bf2f((ushort16)(u0 & 0xFFFF)) + bf2f((ushort16)(u1 & 0xFFFF));
        a1 += bf2f((ushort16)(u0 >> 16))    + bf2f((ushort16)(u1 >> 16));
    }
    for (; k < end; k += 2) {
        int e = k + half;
        if (e < end) {
            uint32 u = ((const uint32*)(hs + (size_t)csr[e] * 64))[l];
            a0 += bf2f((ushort16)(u & 0xFFFF));
            a1 += bf2f((ushort16)(u >> 16));
        }
    }

    // combine halves
    a0 += __shfl_xor(a0, 32, 64);
    a1 += __shfl_xor(a1, 32, 64);

    if (half == 0) {
        float dsc = dis[node];
        float2 bb = ((const float2*)b)[l];
        float2 o;
        o.x = 0.1f + 0.8f / (1.0f + __expf(-(a0 * dsc + bb.x)));
        o.y = 0.1f + 0.8f / (1.0f + __expf(-(a1 * dsc + bb.y)));
        ((float2*)(out + (size_t)node * 64))[l] = o;
    }
}

extern "C" void kernel_launch(void* const* d_in, const int* in_sizes, int n_in,
                              void* d_out, int out_size, void* d_ws, size_t ws_size,
                              hipStream_t stream) {
    const float* x  = (const float*)d_in[0];
    const void*  ei = d_in[1];
    const float* W1 = (const float*)d_in[2];
    const float* b1 = (const float*)d_in[3];
    const float* W2 = (const float*)d_in[4];
    const float* b2 = (const float*)d_in[5];

    const int N = in_sizes[0] / IN_F;   // 100000
    const int E = in_sizes[1] / 2;      // 1600000

    auto alignup = [](size_t v) { return (v + 255) & ~(size_t)255; };
    char* w = (char*)d_ws;
    size_t off = 0;
    int*      flag     = (int*)(w + off);      off = alignup(off + 16);
    int*      counts   = (int*)(w + off);      off = alignup(off + (size_t)N * sizeof(int));
    int*      cursor   = (int*)(w + off);      off = alignup(off + (size_t)N * sizeof(int));
    int*      row_ptr  = (int*)(w + off);      off = alignup(off + (size_t)N * sizeof(int));
    int*      partials = (int*)(w + off);      off = alignup(off + 512 * sizeof(int));
    float*    dis      = (float*)(w + off);    off = alignup(off + (size_t)N * sizeof(float));
    int*      csr      = (int*)(w + off);      off = alignup(off + (size_t)E * sizeof(int));
    ushort16* A        = (ushort16*)(w + off); off = alignup(off + (size_t)N * HID * sizeof(ushort16));
    ushort16* B        = (ushort16*)(w + off); off = alignup(off + (size_t)N * HID * sizeof(ushort16));
    // ~60 MB of ws used

    const int nbN = (N + TPB - 1) / TPB;   // 391
    const int nbE = (E + TPB - 1) / TPB;

    // ---- index layout + degree + CSR build
    detect_i64_kernel<<<1, TPB, 0, stream>>>((const uint32*)ei, 256, flag);
    zero_int_kernel<<<nbN, TPB, 0, stream>>>(counts, N);
    hist_kernel<<<nbE, TPB, 0, stream>>>(ei, E, flag, counts);
    dis_kernel<<<nbN, TPB, 0, stream>>>(counts, dis, N);
    scan_block_kernel<<<nbN, TPB, 0, stream>>>(counts, row_ptr, partials, N);
    scan_partials_kernel<<<1, 512, 0, stream>>>(partials, nbN);
    add_offsets_kernel<<<nbN, TPB, 0, stream>>>(row_ptr, partials, cursor, N);
    fill_kernel<<<nbE, TPB, 0, stream>>>(ei, E, flag, cursor, csr);

    // ---- layer 1: hs1 = bf16((x@W1)*dis) ; h1 = bf16(relu(dis*(hs1[d]+sum hs1[s])+b1))
    gemm_dis_kernel<HID, false><<<(N + 31) / 32, TPB, 0, stream>>>(x, W1, dis, A, N);
    agg128_kernel<<<(N + 3) / 4, TPB, 0, stream>>>(A, csr, row_ptr, counts, dis, b1, B, N);

    // ---- layer 2: hs2 = bf16((h1@W2)*dis) ; out = 0.1+0.8*sigmoid(dis*(hs2[d]+sum hs2[s])+b2)
    gemm_dis_kernel<OUTF, true><<<(N + 63) / 64, TPB, 0, stream>>>(B, W2, dis, A, N);
    agg64_kernel<<<(N + 3) / 4, TPB, 0, stream>>>(A, csr, row_ptr, counts, dis, b2, (float*)d_out, N);
}

// Round 5
// 378.695 us; speedup vs baseline: 11.3193x; 1.2607x over previous
//
#include <hip/hip_runtime.h>
#include <cstdint>
#include <cstddef>

#define IN_F 128
#define HID  128
#define OUTF 64

typedef unsigned int   uint32;
typedef unsigned short ushort16;

static constexpr int TPB = 256;
static constexpr int PT_TILE = 4096;   // edges per partition block
static constexpr int PT_EPT  = 16;     // edges per thread
static constexpr int MAXBK   = 1024;   // max buckets supported by bucketed path

// ---------- bf16 helpers (RNE) ----------
__device__ __forceinline__ float bf2f(ushort16 u) {
    return __uint_as_float(((uint32)u) << 16);
}
__device__ __forceinline__ ushort16 f2bf(float f) {
    uint32 x = __float_as_uint(f);
    x = (x + 0x7FFFu + ((x >> 16) & 1u)) >> 16;
    return (ushort16)x;
}
__device__ __forceinline__ uint32 packbf(float a, float b) {
    return (uint32)f2bf(a) | ((uint32)f2bf(b) << 16);
}

// ---------- index dtype detection (int32 vs int64 layout) ----------
__global__ void detect_i64_kernel(const uint32* __restrict__ p, int npairs, int* __restrict__ flag) {
    __shared__ int anynz;
    if (threadIdx.x == 0) anynz = 0;
    __syncthreads();
    int i = threadIdx.x;
    if (i < npairs && p[2 * i + 1] != 0u) atomicOr(&anynz, 1);
    __syncthreads();
    if (threadIdx.x == 0) *flag = (anynz == 0) ? 1 : 0;
}

__device__ __forceinline__ int load_idx(const void* p, int i, bool i64) {
    return i64 ? (int)((const long long*)p)[i] : ((const int*)p)[i];
}

// ---------- zero ints ----------
__global__ void zero_int_kernel(int* __restrict__ p, int n) {
    int i = blockIdx.x * TPB + threadIdx.x;
    if (i < n) p[i] = 0;
}

// ---------- fused degree-histogram + dst-bucket partition ----------
// Bucket b = dst >> 8 (256 nodes/bucket). Packed entry: src | (dst&255)<<24.
// Block-staged: LDS hist -> scan -> ordered stash -> 1 atomic/bucket -> chunked
// coalesced writes into bbuf bucket regions. This kills the 16x write
// amplification the naive per-edge scatter had (R4: 105 MB writes for 6.4 MB).
__global__ __launch_bounds__(256) void partition_kernel(
    const void* __restrict__ ei, int E, const int* __restrict__ flag,
    int nbuckets, int bcap,
    int* __restrict__ counts, int* __restrict__ bcur, uint32* __restrict__ bbuf)
{
    __shared__ uint32   stash[PT_TILE];
    __shared__ ushort16 bidx[PT_TILE];
    __shared__ int hist[MAXBK];
    __shared__ int scanb[MAXBK];
    __shared__ int gbase[MAXBK];
    __shared__ int sum256[256];

    bool i64 = (*flag != 0);
    int tile0 = blockIdx.x * PT_TILE;
    int tid = threadIdx.x;

    for (int i = tid; i < nbuckets; i += 256) hist[i] = 0;
    __syncthreads();

    uint32 pck[PT_EPT];
    int    lofs[PT_EPT];
    short  bkt[PT_EPT];
#pragma unroll
    for (int j = 0; j < PT_EPT; ++j) {
        int e = tile0 + j * 256 + tid;     // coalesced within each j-step
        if (e < E) {
            int s = load_idx(ei, e, i64);
            int d = load_idx(ei, E + e, i64);
            atomicAdd(&counts[d], 1);      // fused degree histogram
            int b = d >> 8;
            pck[j]  = (uint32)s | ((uint32)(d & 255) << 24);
            bkt[j]  = (short)b;
            lofs[j] = atomicAdd(&hist[b], 1);
        } else bkt[j] = -1;
    }
    __syncthreads();

    // reserve global bucket ranges (one atomic per non-empty bucket)
    for (int i = tid; i < nbuckets; i += 256)
        gbase[i] = hist[i] ? atomicAdd(&bcur[i], hist[i]) : 0;

    // exclusive scan of hist -> scanb (4 elems/thread, block scan of partials)
    {
        int lt = tid * 4;
        int h0 = 0, h1 = 0, h2 = 0, h3 = 0;
        if (lt + 0 < nbuckets) h0 = hist[lt + 0];
        if (lt + 1 < nbuckets) h1 = hist[lt + 1];
        if (lt + 2 < nbuckets) h2 = hist[lt + 2];
        if (lt + 3 < nbuckets) h3 = hist[lt + 3];
        int lsum = h0 + h1 + h2 + h3;
        sum256[tid] = lsum;
        __syncthreads();
        for (int off = 1; off < 256; off <<= 1) {
            int t = (tid >= off) ? sum256[tid - off] : 0;
            __syncthreads();
            sum256[tid] += t;
            __syncthreads();
        }
        int excl = sum256[tid] - lsum;
        if (lt + 0 < nbuckets) scanb[lt + 0] = excl;
        if (lt + 1 < nbuckets) scanb[lt + 1] = excl + h0;
        if (lt + 2 < nbuckets) scanb[lt + 2] = excl + h0 + h1;
        if (lt + 3 < nbuckets) scanb[lt + 3] = excl + h0 + h1 + h2;
    }
    __syncthreads();

    // scatter into bucket-ordered stash
#pragma unroll
    for (int j = 0; j < PT_EPT; ++j) {
        if (bkt[j] >= 0) {
            int p = scanb[bkt[j]] + lofs[j];
            stash[p] = pck[j];
            bidx[p]  = (ushort16)bkt[j];
        }
    }
    __syncthreads();

    // chunked coalesced copy-out
    int total = min(PT_TILE, E - tile0);
    for (int k = tid; k < total; k += 256) {
        int b = bidx[k];
        int dst = gbase[b] + (k - scanb[b]);
        if (dst < bcap) bbuf[(size_t)b * bcap + dst] = stash[k];
    }
}

// ---------- pass B: per-bucket CSR fill (contiguous csr region per block) ----------
__global__ __launch_bounds__(256) void bucket_fill_kernel(
    const uint32* __restrict__ bbuf, const int* __restrict__ bcur,
    const int* __restrict__ row_ptr, int* __restrict__ csr, int N, int bcap)
{
    __shared__ int cur[256];
    int b = blockIdx.x;
    int node = (b << 8) + threadIdx.x;
    cur[threadIdx.x] = (node < N) ? row_ptr[node] : 0;
    __syncthreads();
    int cnt = min(bcur[b], bcap);
    const uint32* src = bbuf + (size_t)b * bcap;
    for (int k = threadIdx.x; k < cnt; k += 256) {
        uint32 p = src[k];
        int dl = p >> 24;
        int pos = atomicAdd(&cur[dl], 1);   // LDS atomic; csr region is L2-local
        csr[pos] = (int)(p & 0xFFFFFF);
    }
}

// ---------- legacy build path (only if N too large for bucketed path) ----------
__global__ void hist_kernel(const void* __restrict__ ei, int E, const int* __restrict__ flag,
                            int* __restrict__ counts) {
    int e = blockIdx.x * TPB + threadIdx.x;
    if (e >= E) return;
    bool i64 = (*flag != 0);
    atomicAdd(&counts[load_idx(ei, E + e, i64)], 1);
}

__global__ void fill_kernel(const void* __restrict__ ei, int E, const int* __restrict__ flag,
                            int* __restrict__ cursor, int* __restrict__ csr_src) {
    int e = blockIdx.x * TPB + threadIdx.x;
    if (e >= E) return;
    bool i64 = (*flag != 0);
    int s = load_idx(ei, e, i64);
    int d = load_idx(ei, E + e, i64);
    int pos = atomicAdd(&cursor[d], 1);
    csr_src[pos] = s;
}

// ---------- dis = rsqrt(deg), deg = counts + 1 (self-loop) ----------
__global__ void dis_kernel(const int* __restrict__ counts, float* __restrict__ dis, int n) {
    int i = blockIdx.x * TPB + threadIdx.x;
    if (i < n) dis[i] = rsqrtf((float)(counts[i] + 1));
}

// ---------- 3-phase exclusive scan over counts -> row_ptr ----------
__global__ void scan_block_kernel(const int* __restrict__ counts, int* __restrict__ excl,
                                  int* __restrict__ partials, int n) {
    __shared__ int tmp[TPB];
    int tid = threadIdx.x, gid = blockIdx.x * TPB + tid;
    int v = (gid < n) ? counts[gid] : 0;
    tmp[tid] = v;
    __syncthreads();
    for (int off = 1; off < TPB; off <<= 1) {
        int t = (tid >= off) ? tmp[tid - off] : 0;
        __syncthreads();
        tmp[tid] += t;
        __syncthreads();
    }
    if (gid < n) excl[gid] = tmp[tid] - v;
    if (tid == TPB - 1) partials[blockIdx.x] = tmp[TPB - 1];
}

__global__ void scan_partials_kernel(int* __restrict__ partials, int nb) {
    __shared__ int tmp[512];
    int tid = threadIdx.x;
    int v = (tid < nb) ? partials[tid] : 0;
    tmp[tid] = v;
    __syncthreads();
    for (int off = 1; off < 512; off <<= 1) {
        int t = (tid >= off) ? tmp[tid - off] : 0;
        __syncthreads();
        tmp[tid] += t;
        __syncthreads();
    }
    if (tid < nb) partials[tid] = tmp[tid] - v;  // exclusive
}

__global__ void add_offsets_kernel(int* __restrict__ excl, const int* __restrict__ partials,
                                   int* __restrict__ cursor, int n) {
    int i = blockIdx.x * TPB + threadIdx.x;
    if (i < n) {
        int v = excl[i] + partials[blockIdx.x];
        excl[i] = v;
        cursor[i] = v;
    }
}

// ---------- GEMM: out[r][:] = bf16( (X[r][:] @ W) * dis[r] )   (K=128 fixed) ----------
template <int C, bool XBF>
__global__ __launch_bounds__(256) void gemm_dis_kernel(
    const void* __restrict__ Xv, const float* __restrict__ W,
    const float* __restrict__ dis, ushort16* __restrict__ out, int nrows)
{
    constexpr int K    = 128;
    constexpr int TX   = C / 4;
    constexpr int TY   = 256 / TX;
    constexpr int ROWS = TY * 4;
    constexpr int XPAD = (C == 64) ? 1 : 0;

    __shared__ float4 Wlds[K][TX];
    __shared__ float4 Xlds[ROWS][K / 4 + XPAD];

    int rowBase = blockIdx.x * ROWS;
    int nr = min(ROWS, nrows - rowBase);

    for (int i = threadIdx.x; i < K * TX; i += 256)
        ((float4*)Wlds)[i] = ((const float4*)W)[i];
    for (int i = threadIdx.x; i < nr * (K / 4); i += 256) {
        int r = i >> 5, kq = i & 31;  // K/4 == 32
        if (XBF) {
            const ushort16* Xb = (const ushort16*)Xv;
            uint2 u = ((const uint2*)(Xb + (size_t)(rowBase + r) * K))[kq];
            float4 f;
            f.x = bf2f((ushort16)(u.x & 0xFFFF)); f.y = bf2f((ushort16)(u.x >> 16));
            f.z = bf2f((ushort16)(u.y & 0xFFFF)); f.w = bf2f((ushort16)(u.y >> 16));
            Xlds[r][kq] = f;
        } else {
            const float* Xf = (const float*)Xv;
            Xlds[r][kq] = ((const float4*)(Xf + (size_t)(rowBase + r) * K))[kq];
        }
    }
    __syncthreads();

    int tx = threadIdx.x % TX, ty = threadIdx.x / TX;
    float acc[4][4] = {};
    for (int kq = 0; kq < K / 4; ++kq) {
        float4 w0 = Wlds[4 * kq + 0][tx];
        float4 w1 = Wlds[4 * kq + 1][tx];
        float4 w2 = Wlds[4 * kq + 2][tx];
        float4 w3 = Wlds[4 * kq + 3][tx];
#pragma unroll
        for (int i2 = 0; i2 < 4; ++i2) {
            float4 xv = Xlds[ty * 4 + i2][kq];
            acc[i2][0] += xv.x * w0.x + xv.y * w1.x + xv.z * w2.x + xv.w * w3.x;
            acc[i2][1] += xv.x * w0.y + xv.y * w1.y + xv.z * w2.y + xv.w * w3.y;
            acc[i2][2] += xv.x * w0.z + xv.y * w1.z + xv.z * w2.z + xv.w * w3.z;
            acc[i2][3] += xv.x * w0.w + xv.y * w1.w + xv.z * w2.w + xv.w * w3.w;
        }
    }
#pragma unroll
    for (int i2 = 0; i2 < 4; ++i2) {
        int r = rowBase + ty * 4 + i2;
        if (r < nrows) {
            float dsc = dis[r];
            uint2 o;
            o.x = packbf(acc[i2][0] * dsc, acc[i2][1] * dsc);
            o.y = packbf(acc[i2][2] * dsc, acc[i2][3] * dsc);
            ((uint2*)(out + (size_t)r * C))[tx] = o;
        }
    }
}

// ---------- aggregation C=128: one wave per node, bf16 in, bf16 out (relu+bias) ----------
__global__ __launch_bounds__(256) void agg128_kernel(
    const ushort16* __restrict__ hs, const int* __restrict__ csr,
    const int* __restrict__ row_ptr, const int* __restrict__ counts,
    const float* __restrict__ dis, const float* __restrict__ b,
    ushort16* __restrict__ out, int n)
{
    int wave = threadIdx.x >> 6;
    int lane = threadIdx.x & 63;
    int node = blockIdx.x * 4 + wave;
    if (node >= n) return;

    float a0, a1;
    {
        uint32 u = ((const uint32*)(hs + (size_t)node * 128))[lane];
        a0 = bf2f((ushort16)(u & 0xFFFF));
        a1 = bf2f((ushort16)(u >> 16));
    }

    int start = row_ptr[node];
    int end   = start + counts[node];
    int k = start;
    for (; k + 1 < end; k += 2) {
        int s0 = csr[k], s1 = csr[k + 1];
        uint32 u0 = ((const uint32*)(hs + (size_t)s0 * 128))[lane];
        uint32 u1 = ((const uint32*)(hs + (size_t)s1 * 128))[lane];
        a0 += bf2f((ushort16)(u0 & 0xFFFF)) + bf2f((ushort16)(u1 & 0xFFFF));
        a1 += bf2f((ushort16)(u0 >> 16))    + bf2f((ushort16)(u1 >> 16));
    }
    if (k < end) {
        uint32 u0 = ((const uint32*)(hs + (size_t)csr[k] * 128))[lane];
        a0 += bf2f((ushort16)(u0 & 0xFFFF));
        a1 += bf2f((ushort16)(u0 >> 16));
    }

    float dsc = dis[node];
    float2 bb = ((const float2*)b)[lane];
    float v0 = fmaxf(a0 * dsc + bb.x, 0.0f);
    float v1 = fmaxf(a1 * dsc + bb.y, 0.0f);
    ((uint32*)(out + (size_t)node * 128))[lane] = packbf(v0, v1);
}

// ---------- aggregation C=64: one wave per node, half-wave per edge ----------
__global__ __launch_bounds__(256) void agg64_kernel(
    const ushort16* __restrict__ hs, const int* __restrict__ csr,
    const int* __restrict__ row_ptr, const int* __restrict__ counts,
    const float* __restrict__ dis, const float* __restrict__ b,
    float* __restrict__ out, int n)
{
    int wave = threadIdx.x >> 6;
    int lane = threadIdx.x & 63;
    int half = lane >> 5;
    int l    = lane & 31;
    int node = blockIdx.x * 4 + wave;
    if (node >= n) return;

    float a0 = 0.0f, a1 = 0.0f;
    if (half == 0) {
        uint32 u = ((const uint32*)(hs + (size_t)node * 64))[l];
        a0 = bf2f((ushort16)(u & 0xFFFF));
        a1 = bf2f((ushort16)(u >> 16));
    }

    int start = row_ptr[node];
    int end   = start + counts[node];
    int k = start;
    for (; k + 3 < end; k += 4) {
        int s0 = csr[k + half];
        int s1 = csr[k + 2 + half];
        uint32 u0 = ((const uint32*)(hs + (size_t)s0 * 64))[l];
        uint32 u1 = ((const uint32*)(hs + (size_t)s1 * 64))[l];
        a0 += bf2f((ushort16)(u0 & 0xFFFF)) + bf2f((ushort16)(u1 & 0xFFFF));
        a1 += bf2f((ushort16)(u0 >> 16))    + bf2f((ushort16)(u1 >> 16));
    }
    for (; k < end; k += 2) {
        int e = k + half;
        if (e < end) {
            uint32 u = ((const uint32*)(hs + (size_t)csr[e] * 64))[l];
            a0 += bf2f((ushort16)(u & 0xFFFF));
            a1 += bf2f((ushort16)(u >> 16));
        }
    }

    a0 += __shfl_xor(a0, 32, 64);
    a1 += __shfl_xor(a1, 32, 64);

    if (half == 0) {
        float dsc = dis[node];
        float2 bb = ((const float2*)b)[l];
        float2 o;
        o.x = 0.1f + 0.8f / (1.0f + __expf(-(a0 * dsc + bb.x)));
        o.y = 0.1f + 0.8f / (1.0f + __expf(-(a1 * dsc + bb.y)));
        ((float2*)(out + (size_t)node * 64))[l] = o;
    }
}

extern "C" void kernel_launch(void* const* d_in, const int* in_sizes, int n_in,
                              void* d_out, int out_size, void* d_ws, size_t ws_size,
                              hipStream_t stream) {
    const float* x  = (const float*)d_in[0];
    const void*  ei = d_in[1];
    const float* W1 = (const float*)d_in[2];
    const float* b1 = (const float*)d_in[3];
    const float* W2 = (const float*)d_in[4];
    const float* b2 = (const float*)d_in[5];

    const int N = in_sizes[0] / IN_F;   // 100000
    const int E = in_sizes[1] / 2;      // 1600000

    const int nbuckets = (N + 255) >> 8;                 // 391
    const int bcap     = (int)(2 * ((long long)E / (nbuckets > 0 ? nbuckets : 1)) + 2048);
    const bool bucketed = (nbuckets <= MAXBK) && (N <= (1 << 24));

    auto alignup = [](size_t v) { return (v + 255) & ~(size_t)255; };
    char* w = (char*)d_ws;
    size_t off = 0;
    int*      flag     = (int*)(w + off);      off = alignup(off + 16);
    // counts and bcur: ONE contiguous block, zeroed together (R2 lesson).
    int*      counts   = (int*)(w + off);      off = alignup(off + (size_t)(N + MAXBK) * sizeof(int));
    int*      bcur     = counts + N;
    int*      cursor   = (int*)(w + off);      off = alignup(off + (size_t)N * sizeof(int));
    int*      row_ptr  = (int*)(w + off);      off = alignup(off + (size_t)N * sizeof(int));
    int*      partials = (int*)(w + off);      off = alignup(off + 512 * sizeof(int));
    float*    dis      = (float*)(w + off);    off = alignup(off + (size_t)N * sizeof(float));
    int*      csr      = (int*)(w + off);      off = alignup(off + (size_t)E * sizeof(int));
    uint32*   bbuf     = (uint32*)(w + off);   off = alignup(off + (size_t)nbuckets * bcap * sizeof(uint32));
    ushort16* A        = (ushort16*)(w + off); off = alignup(off + (size_t)N * HID * sizeof(ushort16));
    ushort16* B        = (ushort16*)(w + off); off = alignup(off + (size_t)N * HID * sizeof(ushort16));
    // ~76 MB of ws used

    const int nbN = (N + TPB - 1) / TPB;   // 391
    const int nbE = (E + TPB - 1) / TPB;

    detect_i64_kernel<<<1, TPB, 0, stream>>>((const uint32*)ei, 256, flag);
    zero_int_kernel<<<(N + MAXBK + TPB - 1) / TPB, TPB, 0, stream>>>(counts, N + MAXBK);

    if (bucketed) {
        partition_kernel<<<(E + PT_TILE - 1) / PT_TILE, TPB, 0, stream>>>(
            ei, E, flag, nbuckets, bcap, counts, bcur, bbuf);
        dis_kernel<<<nbN, TPB, 0, stream>>>(counts, dis, N);
        scan_block_kernel<<<nbN, TPB, 0, stream>>>(counts, row_ptr, partials, N);
        scan_partials_kernel<<<1, 512, 0, stream>>>(partials, nbN);
        add_offsets_kernel<<<nbN, TPB, 0, stream>>>(row_ptr, partials, cursor, N);
        bucket_fill_kernel<<<nbuckets, TPB, 0, stream>>>(bbuf, bcur, row_ptr, csr, N, bcap);
    } else {
        hist_kernel<<<nbE, TPB, 0, stream>>>(ei, E, flag, counts);
        dis_kernel<<<nbN, TPB, 0, stream>>>(counts, dis, N);
        scan_block_kernel<<<nbN, TPB, 0, stream>>>(counts, row_ptr, partials, N);
        scan_partials_kernel<<<1, 512, 0, stream>>>(partials, nbN);
        add_offsets_kernel<<<nbN, TPB, 0, stream>>>(row_ptr, partials, cursor, N);
        fill_kernel<<<nbE, TPB, 0, stream>>>(ei, E, flag, cursor, csr);
    }

    // ---- layer 1
    gemm_dis_kernel<HID, false><<<(N + 31) / 32, TPB, 0, stream>>>(x, W1, dis, A, N);
    agg128_kernel<<<(N + 3) / 4, TPB, 0, stream>>>(A, csr, row_ptr, counts, dis, b1, B, N);

    // ---- layer 2
    gemm_dis_kernel<OUTF, true><<<(N + 63) / 64, TPB, 0, stream>>>(B, W2, dis, A, N);
    agg64_kernel<<<(N + 3) / 4, TPB, 0, stream>>>(A, csr, row_ptr, counts, dis, b2, (float*)d_out, N);
}

// Round 6
// 333.990 us; speedup vs baseline: 12.8344x; 1.1339x over previous
//
#include <hip/hip_runtime.h>
#include <cstdint>
#include <cstddef>

#define IN_F 128
#define HID  128
#define OUTF 64

typedef unsigned int   uint32;
typedef unsigned short ushort16;

static constexpr int TPB = 256;
static constexpr int PT_TILE = 4096;   // edges per partition block
static constexpr int PT_EPT  = 16;     // edges per thread
static constexpr int MAXBK   = 1024;   // max buckets supported by bucketed path

// ---------- bf16 helpers (RNE) ----------
__device__ __forceinline__ float bf2f(ushort16 u) {
    return __uint_as_float(((uint32)u) << 16);
}
__device__ __forceinline__ float bflo(uint32 u) { return __uint_as_float(u << 16); }
__device__ __forceinline__ float bfhi(uint32 u) { return __uint_as_float(u & 0xFFFF0000u); }
__device__ __forceinline__ ushort16 f2bf(float f) {
    uint32 x = __float_as_uint(f);
    x = (x + 0x7FFFu + ((x >> 16) & 1u)) >> 16;
    return (ushort16)x;
}
__device__ __forceinline__ uint32 packbf(float a, float b) {
    return (uint32)f2bf(a) | ((uint32)f2bf(b) << 16);
}

// ---------- index dtype detection (int32 vs int64 layout) ----------
__global__ void detect_i64_kernel(const uint32* __restrict__ p, int npairs, int* __restrict__ flag) {
    __shared__ int anynz;
    if (threadIdx.x == 0) anynz = 0;
    __syncthreads();
    int i = threadIdx.x;
    if (i < npairs && p[2 * i + 1] != 0u) atomicOr(&anynz, 1);
    __syncthreads();
    if (threadIdx.x == 0) *flag = (anynz == 0) ? 1 : 0;
}

__device__ __forceinline__ int load_idx(const void* p, int i, bool i64) {
    return i64 ? (int)((const long long*)p)[i] : ((const int*)p)[i];
}

// ---------- zero ints ----------
__global__ void zero_int_kernel(int* __restrict__ p, int n) {
    int i = blockIdx.x * TPB + threadIdx.x;
    if (i < n) p[i] = 0;
}

// ---------- fused degree-histogram + dst-bucket partition ----------
__global__ __launch_bounds__(256) void partition_kernel(
    const void* __restrict__ ei, int E, const int* __restrict__ flag,
    int nbuckets, int bcap,
    int* __restrict__ counts, int* __restrict__ bcur, uint32* __restrict__ bbuf)
{
    __shared__ uint32   stash[PT_TILE];
    __shared__ ushort16 bidx[PT_TILE];
    __shared__ int hist[MAXBK];
    __shared__ int scanb[MAXBK];
    __shared__ int gbase[MAXBK];
    __shared__ int sum256[256];

    bool i64 = (*flag != 0);
    int tile0 = blockIdx.x * PT_TILE;
    int tid = threadIdx.x;

    for (int i = tid; i < nbuckets; i += 256) hist[i] = 0;
    __syncthreads();

    uint32 pck[PT_EPT];
    int    lofs[PT_EPT];
    short  bkt[PT_EPT];
#pragma unroll
    for (int j = 0; j < PT_EPT; ++j) {
        int e = tile0 + j * 256 + tid;
        if (e < E) {
            int s = load_idx(ei, e, i64);
            int d = load_idx(ei, E + e, i64);
            atomicAdd(&counts[d], 1);
            int b = d >> 8;
            pck[j]  = (uint32)s | ((uint32)(d & 255) << 24);
            bkt[j]  = (short)b;
            lofs[j] = atomicAdd(&hist[b], 1);
        } else bkt[j] = -1;
    }
    __syncthreads();

    for (int i = tid; i < nbuckets; i += 256)
        gbase[i] = hist[i] ? atomicAdd(&bcur[i], hist[i]) : 0;

    {
        int lt = tid * 4;
        int h0 = 0, h1 = 0, h2 = 0, h3 = 0;
        if (lt + 0 < nbuckets) h0 = hist[lt + 0];
        if (lt + 1 < nbuckets) h1 = hist[lt + 1];
        if (lt + 2 < nbuckets) h2 = hist[lt + 2];
        if (lt + 3 < nbuckets) h3 = hist[lt + 3];
        int lsum = h0 + h1 + h2 + h3;
        sum256[tid] = lsum;
        __syncthreads();
        for (int off = 1; off < 256; off <<= 1) {
            int t = (tid >= off) ? sum256[tid - off] : 0;
            __syncthreads();
            sum256[tid] += t;
            __syncthreads();
        }
        int excl = sum256[tid] - lsum;
        if (lt + 0 < nbuckets) scanb[lt + 0] = excl;
        if (lt + 1 < nbuckets) scanb[lt + 1] = excl + h0;
        if (lt + 2 < nbuckets) scanb[lt + 2] = excl + h0 + h1;
        if (lt + 3 < nbuckets) scanb[lt + 3] = excl + h0 + h1 + h2;
    }
    __syncthreads();

#pragma unroll
    for (int j = 0; j < PT_EPT; ++j) {
        if (bkt[j] >= 0) {
            int p = scanb[bkt[j]] + lofs[j];
            stash[p] = pck[j];
            bidx[p]  = (ushort16)bkt[j];
        }
    }
    __syncthreads();

    int total = min(PT_TILE, E - tile0);
    for (int k = tid; k < total; k += 256) {
        int b = bidx[k];
        int dst = gbase[b] + (k - scanb[b]);
        if (dst < bcap) bbuf[(size_t)b * bcap + dst] = stash[k];
    }
}

// ---------- pass B: per-bucket CSR fill ----------
__global__ __launch_bounds__(256) void bucket_fill_kernel(
    const uint32* __restrict__ bbuf, const int* __restrict__ bcur,
    const int* __restrict__ row_ptr, int* __restrict__ csr, int N, int bcap)
{
    __shared__ int cur[256];
    int b = blockIdx.x;
    int node = (b << 8) + threadIdx.x;
    cur[threadIdx.x] = (node < N) ? row_ptr[node] : 0;
    __syncthreads();
    int cnt = min(bcur[b], bcap);
    const uint32* src = bbuf + (size_t)b * bcap;
    for (int k = threadIdx.x; k < cnt; k += 256) {
        uint32 p = src[k];
        int dl = p >> 24;
        int pos = atomicAdd(&cur[dl], 1);
        csr[pos] = (int)(p & 0xFFFFFF);
    }
}

// ---------- legacy build path ----------
__global__ void hist_kernel(const void* __restrict__ ei, int E, const int* __restrict__ flag,
                            int* __restrict__ counts) {
    int e = blockIdx.x * TPB + threadIdx.x;
    if (e >= E) return;
    bool i64 = (*flag != 0);
    atomicAdd(&counts[load_idx(ei, E + e, i64)], 1);
}

__global__ void fill_kernel(const void* __restrict__ ei, int E, const int* __restrict__ flag,
                            int* __restrict__ cursor, int* __restrict__ csr_src) {
    int e = blockIdx.x * TPB + threadIdx.x;
    if (e >= E) return;
    bool i64 = (*flag != 0);
    int s = load_idx(ei, e, i64);
    int d = load_idx(ei, E + e, i64);
    int pos = atomicAdd(&cursor[d], 1);
    csr_src[pos] = s;
}

// ---------- dis = rsqrt(deg) ----------
__global__ void dis_kernel(const int* __restrict__ counts, float* __restrict__ dis, int n) {
    int i = blockIdx.x * TPB + threadIdx.x;
    if (i < n) dis[i] = rsqrtf((float)(counts[i] + 1));
}

// ---------- scans ----------
__global__ void scan_block_kernel(const int* __restrict__ counts, int* __restrict__ excl,
                                  int* __restrict__ partials, int n) {
    __shared__ int tmp[TPB];
    int tid = threadIdx.x, gid = blockIdx.x * TPB + tid;
    int v = (gid < n) ? counts[gid] : 0;
    tmp[tid] = v;
    __syncthreads();
    for (int off = 1; off < TPB; off <<= 1) {
        int t = (tid >= off) ? tmp[tid - off] : 0;
        __syncthreads();
        tmp[tid] += t;
        __syncthreads();
    }
    if (gid < n) excl[gid] = tmp[tid] - v;
    if (tid == TPB - 1) partials[blockIdx.x] = tmp[TPB - 1];
}

__global__ void scan_partials_kernel(int* __restrict__ partials, int nb) {
    __shared__ int tmp[512];
    int tid = threadIdx.x;
    int v = (tid < nb) ? partials[tid] : 0;
    tmp[tid] = v;
    __syncthreads();
    for (int off = 1; off < 512; off <<= 1) {
        int t = (tid >= off) ? tmp[tid - off] : 0;
        __syncthreads();
        tmp[tid] += t;
        __syncthreads();
    }
    if (tid < nb) partials[tid] = tmp[tid] - v;
}

__global__ void add_offsets_kernel(int* __restrict__ excl, const int* __restrict__ partials,
                                   int* __restrict__ cursor, int n) {
    int i = blockIdx.x * TPB + threadIdx.x;
    if (i < n) {
        int v = excl[i] + partials[blockIdx.x];
        excl[i] = v;
        cursor[i] = v;
    }
}

// ---------- GEMM: out[r][:] = bf16( (X[r][:] @ W) * dis[r] ) ----------
template <int C, bool XBF>
__global__ __launch_bounds__(256) void gemm_dis_kernel(
    const void* __restrict__ Xv, const float* __restrict__ W,
    const float* __restrict__ dis, ushort16* __restrict__ out, int nrows)
{
    constexpr int K    = 128;
    constexpr int TX   = C / 4;
    constexpr int TY   = 256 / TX;
    constexpr int ROWS = TY * 4;
    constexpr int XPAD = (C == 64) ? 1 : 0;

    __shared__ float4 Wlds[K][TX];
    __shared__ float4 Xlds[ROWS][K / 4 + XPAD];

    int rowBase = blockIdx.x * ROWS;
    int nr = min(ROWS, nrows - rowBase);

    for (int i = threadIdx.x; i < K * TX; i += 256)
        ((float4*)Wlds)[i] = ((const float4*)W)[i];
    for (int i = threadIdx.x; i < nr * (K / 4); i += 256) {
        int r = i >> 5, kq = i & 31;
        if (XBF) {
            const ushort16* Xb = (const ushort16*)Xv;
            uint2 u = ((const uint2*)(Xb + (size_t)(rowBase + r) * K))[kq];
            float4 f;
            f.x = bflo(u.x); f.y = bfhi(u.x);
            f.z = bflo(u.y); f.w = bfhi(u.y);
            Xlds[r][kq] = f;
        } else {
            const float* Xf = (const float*)Xv;
            Xlds[r][kq] = ((const float4*)(Xf + (size_t)(rowBase + r) * K))[kq];
        }
    }
    __syncthreads();

    int tx = threadIdx.x % TX, ty = threadIdx.x / TX;
    float acc[4][4] = {};
    for (int kq = 0; kq < K / 4; ++kq) {
        float4 w0 = Wlds[4 * kq + 0][tx];
        float4 w1 = Wlds[4 * kq + 1][tx];
        float4 w2 = Wlds[4 * kq + 2][tx];
        float4 w3 = Wlds[4 * kq + 3][tx];
#pragma unroll
        for (int i2 = 0; i2 < 4; ++i2) {
            float4 xv = Xlds[ty * 4 + i2][kq];
            acc[i2][0] += xv.x * w0.x + xv.y * w1.x + xv.z * w2.x + xv.w * w3.x;
            acc[i2][1] += xv.x * w0.y + xv.y * w1.y + xv.z * w2.y + xv.w * w3.y;
            acc[i2][2] += xv.x * w0.z + xv.y * w1.z + xv.z * w2.z + xv.w * w3.z;
            acc[i2][3] += xv.x * w0.w + xv.y * w1.w + xv.z * w2.w + xv.w * w3.w;
        }
    }
#pragma unroll
    for (int i2 = 0; i2 < 4; ++i2) {
        int r = rowBase + ty * 4 + i2;
        if (r < nrows) {
            float dsc = dis[r];
            uint2 o;
            o.x = packbf(acc[i2][0] * dsc, acc[i2][1] * dsc);
            o.y = packbf(acc[i2][2] * dsc, acc[i2][3] * dsc);
            ((uint2*)(out + (size_t)r * C))[tx] = o;
        }
    }
}

// ---------- aggregation C=128: wave per node, HALF-wave per edge (uint2/lane) ----------
// lanes 0-31 = half 0, lanes 32-63 = half 1. Each half gathers different edges;
// 8 edges / wave-iter, 4 independent 8B loads in flight per lane (MLP depth fix:
// R5 counters showed latency-bound — 4 TB/s payload, VALUBusy 31%, all pipes idle).
__global__ __launch_bounds__(256) void agg128_kernel(
    const uint32* __restrict__ hs, const int* __restrict__ csr,
    const int* __restrict__ row_ptr, const int* __restrict__ counts,
    const float* __restrict__ dis, const float* __restrict__ b,
    uint32* __restrict__ out, int n)
{
    int wave = threadIdx.x >> 6;
    int lane = threadIdx.x & 63;
    int h    = lane >> 5;
    int sl   = lane & 31;
    int node = blockIdx.x * 4 + wave;
    if (node >= n) return;

    const uint2* hsv = (const uint2*)hs;   // row = 32 uint2 (128 bf16)
    float a0 = 0.f, a1 = 0.f, a2 = 0.f, a3 = 0.f;
    if (h == 0) {   // self-loop counted once
        uint2 u = hsv[(size_t)node * 32 + sl];
        a0 = bflo(u.x); a1 = bfhi(u.x); a2 = bflo(u.y); a3 = bfhi(u.y);
    }

    int start = row_ptr[node];
    int end   = start + counts[node];
    int k = start;
    for (; k + 7 < end; k += 8) {       // half h takes 4 edges: k+4h .. k+4h+3
        int base = k + (h << 2);
        int s0 = csr[base], s1 = csr[base + 1], s2 = csr[base + 2], s3 = csr[base + 3];
        uint2 u0 = hsv[(size_t)s0 * 32 + sl];
        uint2 u1 = hsv[(size_t)s1 * 32 + sl];
        uint2 u2 = hsv[(size_t)s2 * 32 + sl];
        uint2 u3 = hsv[(size_t)s3 * 32 + sl];
        a0 += bflo(u0.x) + bflo(u1.x) + bflo(u2.x) + bflo(u3.x);
        a1 += bfhi(u0.x) + bfhi(u1.x) + bfhi(u2.x) + bfhi(u3.x);
        a2 += bflo(u0.y) + bflo(u1.y) + bflo(u2.y) + bflo(u3.y);
        a3 += bfhi(u0.y) + bfhi(u1.y) + bfhi(u2.y) + bfhi(u3.y);
    }
    for (; k + 3 < end; k += 4) {       // half h takes 2 edges: k+2h, k+2h+1
        int base = k + (h << 1);
        int s0 = csr[base], s1 = csr[base + 1];
        uint2 u0 = hsv[(size_t)s0 * 32 + sl];
        uint2 u1 = hsv[(size_t)s1 * 32 + sl];
        a0 += bflo(u0.x) + bflo(u1.x);
        a1 += bfhi(u0.x) + bfhi(u1.x);
        a2 += bflo(u0.y) + bflo(u1.y);
        a3 += bfhi(u0.y) + bfhi(u1.y);
    }
    for (; k < end; k += 2) {           // 1-3 remaining
        int e = k + h;
        if (e < end) {
            uint2 u = hsv[(size_t)csr[e] * 32 + sl];
            a0 += bflo(u.x); a1 += bfhi(u.x); a2 += bflo(u.y); a3 += bfhi(u.y);
        }
    }

    a0 += __shfl_xor(a0, 32, 64);
    a1 += __shfl_xor(a1, 32, 64);
    a2 += __shfl_xor(a2, 32, 64);
    a3 += __shfl_xor(a3, 32, 64);

    if (h == 0) {
        float dsc = dis[node];
        float4 bb = ((const float4*)b)[sl];
        float v0 = fmaxf(a0 * dsc + bb.x, 0.0f);
        float v1 = fmaxf(a1 * dsc + bb.y, 0.0f);
        float v2 = fmaxf(a2 * dsc + bb.z, 0.0f);
        float v3 = fmaxf(a3 * dsc + bb.w, 0.0f);
        uint2 o; o.x = packbf(v0, v1); o.y = packbf(v2, v3);
        ((uint2*)out)[(size_t)node * 32 + sl] = o;
    }
}

// ---------- aggregation C=64: wave per node, QUARTER-wave per edge (uint2/lane) ----------
__global__ __launch_bounds__(256) void agg64_kernel(
    const uint32* __restrict__ hs, const int* __restrict__ csr,
    const int* __restrict__ row_ptr, const int* __restrict__ counts,
    const float* __restrict__ dis, const float* __restrict__ b,
    float* __restrict__ out, int n)
{
    int wave = threadIdx.x >> 6;
    int lane = threadIdx.x & 63;
    int q    = lane >> 4;        // quarter 0..3
    int sl   = lane & 15;
    int node = blockIdx.x * 4 + wave;
    if (node >= n) return;

    const uint2* hsv = (const uint2*)hs;   // row = 16 uint2 (64 bf16)
    float a0 = 0.f, a1 = 0.f, a2 = 0.f, a3 = 0.f;
    if (q == 0) {
        uint2 u = hsv[(size_t)node * 16 + sl];
        a0 = bflo(u.x); a1 = bfhi(u.x); a2 = bflo(u.y); a3 = bfhi(u.y);
    }

    int start = row_ptr[node];
    int end   = start + counts[node];
    int k = start;
    for (; k + 7 < end; k += 8) {       // quarter q takes edges k+2q, k+2q+1
        int base = k + (q << 1);
        int s0 = csr[base], s1 = csr[base + 1];
        uint2 u0 = hsv[(size_t)s0 * 16 + sl];
        uint2 u1 = hsv[(size_t)s1 * 16 + sl];
        a0 += bflo(u0.x) + bflo(u1.x);
        a1 += bfhi(u0.x) + bfhi(u1.x);
        a2 += bflo(u0.y) + bflo(u1.y);
        a3 += bfhi(u0.y) + bfhi(u1.y);
    }
    for (; k < end; k += 4) {           // quarter q takes edge k+q (guarded)
        int e = k + q;
        if (e < end) {
            uint2 u = hsv[(size_t)csr[e] * 16 + sl];
            a0 += bflo(u.x); a1 += bfhi(u.x); a2 += bflo(u.y); a3 += bfhi(u.y);
        }
    }

    a0 += __shfl_xor(a0, 16, 64);  a0 += __shfl_xor(a0, 32, 64);
    a1 += __shfl_xor(a1, 16, 64);  a1 += __shfl_xor(a1, 32, 64);
    a2 += __shfl_xor(a2, 16, 64);  a2 += __shfl_xor(a2, 32, 64);
    a3 += __shfl_xor(a3, 16, 64);  a3 += __shfl_xor(a3, 32, 64);

    if (q == 0) {
        float dsc = dis[node];
        float4 bb = ((const float4*)b)[sl];
        float4 o;
        o.x = 0.1f + 0.8f / (1.0f + __expf(-(a0 * dsc + bb.x)));
        o.y = 0.1f + 0.8f / (1.0f + __expf(-(a1 * dsc + bb.y)));
        o.z = 0.1f + 0.8f / (1.0f + __expf(-(a2 * dsc + bb.z)));
        o.w = 0.1f + 0.8f / (1.0f + __expf(-(a3 * dsc + bb.w)));
        ((float4*)out)[(size_t)node * 16 + sl] = o;
    }
}

extern "C" void kernel_launch(void* const* d_in, const int* in_sizes, int n_in,
                              void* d_out, int out_size, void* d_ws, size_t ws_size,
                              hipStream_t stream) {
    const float* x  = (const float*)d_in[0];
    const void*  ei = d_in[1];
    const float* W1 = (const float*)d_in[2];
    const float* b1 = (const float*)d_in[3];
    const float* W2 = (const float*)d_in[4];
    const float* b2 = (const float*)d_in[5];

    const int N = in_sizes[0] / IN_F;   // 100000
    const int E = in_sizes[1] / 2;      // 1600000

    const int nbuckets = (N + 255) >> 8;                 // 391
    const int bcap     = (int)(2 * ((long long)E / (nbuckets > 0 ? nbuckets : 1)) + 2048);
    const bool bucketed = (nbuckets <= MAXBK) && (N <= (1 << 24));

    auto alignup = [](size_t v) { return (v + 255) & ~(size_t)255; };
    char* w = (char*)d_ws;
    size_t off = 0;
    int*      flag     = (int*)(w + off);      off = alignup(off + 16);
    int*      counts   = (int*)(w + off);      off = alignup(off + (size_t)(N + MAXBK) * sizeof(int));
    int*      bcur     = counts + N;
    int*      cursor   = (int*)(w + off);      off = alignup(off + (size_t)N * sizeof(int));
    int*      row_ptr  = (int*)(w + off);      off = alignup(off + (size_t)N * sizeof(int));
    int*      partials = (int*)(w + off);      off = alignup(off + 512 * sizeof(int));
    float*    dis      = (float*)(w + off);    off = alignup(off + (size_t)N * sizeof(float));
    int*      csr      = (int*)(w + off);      off = alignup(off + (size_t)E * sizeof(int));
    uint32*   bbuf     = (uint32*)(w + off);   off = alignup(off + (size_t)nbuckets * bcap * sizeof(uint32));
    uint32*   A        = (uint32*)(w + off);   off = alignup(off + (size_t)N * HID * sizeof(ushort16));
    uint32*   B        = (uint32*)(w + off);   off = alignup(off + (size_t)N * HID * sizeof(ushort16));

    const int nbN = (N + TPB - 1) / TPB;   // 391
    const int nbE = (E + TPB - 1) / TPB;

    detect_i64_kernel<<<1, TPB, 0, stream>>>((const uint32*)ei, 256, flag);
    zero_int_kernel<<<(N + MAXBK + TPB - 1) / TPB, TPB, 0, stream>>>(counts, N + MAXBK);

    if (bucketed) {
        partition_kernel<<<(E + PT_TILE - 1) / PT_TILE, TPB, 0, stream>>>(
            ei, E, flag, nbuckets, bcap, counts, bcur, bbuf);
        dis_kernel<<<nbN, TPB, 0, stream>>>(counts, dis, N);
        scan_block_kernel<<<nbN, TPB, 0, stream>>>(counts, row_ptr, partials, N);
        scan_partials_kernel<<<1, 512, 0, stream>>>(partials, nbN);
        add_offsets_kernel<<<nbN, TPB, 0, stream>>>(row_ptr, partials, cursor, N);
        bucket_fill_kernel<<<nbuckets, TPB, 0, stream>>>(bbuf, bcur, row_ptr, csr, N, bcap);
    } else {
        hist_kernel<<<nbE, TPB, 0, stream>>>(ei, E, flag, counts);
        dis_kernel<<<nbN, TPB, 0, stream>>>(counts, dis, N);
        scan_block_kernel<<<nbN, TPB, 0, stream>>>(counts, row_ptr, partials, N);
        scan_partials_kernel<<<1, 512, 0, stream>>>(partials, nbN);
        add_offsets_kernel<<<nbN, TPB, 0, stream>>>(row_ptr, partials, cursor, N);
        fill_kernel<<<nbE, TPB, 0, stream>>>(ei, E, flag, cursor, csr);
    }

    // ---- layer 1
    gemm_dis_kernel<HID, false><<<(N + 31) / 32, TPB, 0, stream>>>(x, W1, dis, (ushort16*)A, N);
    agg128_kernel<<<(N + 3) / 4, TPB, 0, stream>>>(A, csr, row_ptr, counts, dis, b1, B, N);

    // ---- layer 2
    gemm_dis_kernel<OUTF, true><<<(N + 63) / 64, TPB, 0, stream>>>(B, W2, dis, (ushort16*)A, N);
    agg64_kernel<<<(N + 3) / 4, TPB, 0, stream>>>(A, csr, row_ptr, counts, dis, b2, (float*)d_out, N);
}

// Round 7
// 259.403 us; speedup vs baseline: 16.5247x; 1.2875x over previous
//
#include <hip/hip_runtime.h>
#include <cstdint>
#include <cstddef>

#define IN_F 128
#define HID  128
#define OUTF 64

typedef unsigned int   uint32;
typedef unsigned short ushort16;

using frag_ab = __attribute__((ext_vector_type(8))) short;   // 8 bf16
using frag_cd = __attribute__((ext_vector_type(4))) float;   // 4 f32

static constexpr int TPB = 256;
static constexpr int PT_TILE = 4096;   // edges per partition block
static constexpr int PT_EPT  = 16;     // edges per thread
static constexpr int MAXBK   = 1024;   // max buckets supported by bucketed path

// ---------- bf16 helpers (RNE) ----------
__device__ __forceinline__ float bflo(uint32 u) { return __uint_as_float(u << 16); }
__device__ __forceinline__ float bfhi(uint32 u) { return __uint_as_float(u & 0xFFFF0000u); }
__device__ __forceinline__ ushort16 f2bf(float f) {
    uint32 x = __float_as_uint(f);
    x = (x + 0x7FFFu + ((x >> 16) & 1u)) >> 16;
    return (ushort16)x;
}
__device__ __forceinline__ uint32 packbf(float a, float b) {
    return (uint32)f2bf(a) | ((uint32)f2bf(b) << 16);
}

// ---------- index dtype detection (int32 vs int64 layout) ----------
__global__ void detect_i64_kernel(const uint32* __restrict__ p, int npairs, int* __restrict__ flag) {
    __shared__ int anynz;
    if (threadIdx.x == 0) anynz = 0;
    __syncthreads();
    int i = threadIdx.x;
    if (i < npairs && p[2 * i + 1] != 0u) atomicOr(&anynz, 1);
    __syncthreads();
    if (threadIdx.x == 0) *flag = (anynz == 0) ? 1 : 0;
}

__device__ __forceinline__ int load_idx(const void* p, int i, bool i64) {
    return i64 ? (int)((const long long*)p)[i] : ((const int*)p)[i];
}

// ---------- zero ints ----------
__global__ void zero_int_kernel(int* __restrict__ p, int n) {
    int i = blockIdx.x * TPB + threadIdx.x;
    if (i < n) p[i] = 0;
}

// ---------- fused degree-histogram + dst-bucket partition ----------
__global__ __launch_bounds__(256) void partition_kernel(
    const void* __restrict__ ei, int E, const int* __restrict__ flag,
    int nbuckets, int bcap,
    int* __restrict__ counts, int* __restrict__ bcur, uint32* __restrict__ bbuf)
{
    __shared__ uint32   stash[PT_TILE];
    __shared__ ushort16 bidx[PT_TILE];
    __shared__ int hist[MAXBK];
    __shared__ int scanb[MAXBK];
    __shared__ int gbase[MAXBK];
    __shared__ int sum256[256];

    bool i64 = (*flag != 0);
    int tile0 = blockIdx.x * PT_TILE;
    int tid = threadIdx.x;

    for (int i = tid; i < nbuckets; i += 256) hist[i] = 0;
    __syncthreads();

    uint32 pck[PT_EPT];
    int    lofs[PT_EPT];
    short  bkt[PT_EPT];
#pragma unroll
    for (int j = 0; j < PT_EPT; ++j) {
        int e = tile0 + j * 256 + tid;
        if (e < E) {
            int s = load_idx(ei, e, i64);
            int d = load_idx(ei, E + e, i64);
            atomicAdd(&counts[d], 1);
            int b = d >> 8;
            pck[j]  = (uint32)s | ((uint32)(d & 255) << 24);
            bkt[j]  = (short)b;
            lofs[j] = atomicAdd(&hist[b], 1);
        } else bkt[j] = -1;
    }
    __syncthreads();

    for (int i = tid; i < nbuckets; i += 256)
        gbase[i] = hist[i] ? atomicAdd(&bcur[i], hist[i]) : 0;

    {
        int lt = tid * 4;
        int h0 = 0, h1 = 0, h2 = 0, h3 = 0;
        if (lt + 0 < nbuckets) h0 = hist[lt + 0];
        if (lt + 1 < nbuckets) h1 = hist[lt + 1];
        if (lt + 2 < nbuckets) h2 = hist[lt + 2];
        if (lt + 3 < nbuckets) h3 = hist[lt + 3];
        int lsum = h0 + h1 + h2 + h3;
        sum256[tid] = lsum;
        __syncthreads();
        for (int off = 1; off < 256; off <<= 1) {
            int t = (tid >= off) ? sum256[tid - off] : 0;
            __syncthreads();
            sum256[tid] += t;
            __syncthreads();
        }
        int excl = sum256[tid] - lsum;
        if (lt + 0 < nbuckets) scanb[lt + 0] = excl;
        if (lt + 1 < nbuckets) scanb[lt + 1] = excl + h0;
        if (lt + 2 < nbuckets) scanb[lt + 2] = excl + h0 + h1;
        if (lt + 3 < nbuckets) scanb[lt + 3] = excl + h0 + h1 + h2;
    }
    __syncthreads();

#pragma unroll
    for (int j = 0; j < PT_EPT; ++j) {
        if (bkt[j] >= 0) {
            int p = scanb[bkt[j]] + lofs[j];
            stash[p] = pck[j];
            bidx[p]  = (ushort16)bkt[j];
        }
    }
    __syncthreads();

    int total = min(PT_TILE, E - tile0);
    for (int k = tid; k < total; k += 256) {
        int b = bidx[k];
        int dst = gbase[b] + (k - scanb[b]);
        if (dst < bcap) bbuf[(size_t)b * bcap + dst] = stash[k];
    }
}

// ---------- pass B: per-bucket CSR fill ----------
__global__ __launch_bounds__(256) void bucket_fill_kernel(
    const uint32* __restrict__ bbuf, const int* __restrict__ bcur,
    const int* __restrict__ row_ptr, int* __restrict__ csr, int N, int bcap)
{
    __shared__ int cur[256];
    int b = blockIdx.x;
    int node = (b << 8) + threadIdx.x;
    cur[threadIdx.x] = (node < N) ? row_ptr[node] : 0;
    __syncthreads();
    int cnt = min(bcur[b], bcap);
    const uint32* src = bbuf + (size_t)b * bcap;
    for (int k = threadIdx.x; k < cnt; k += 256) {
        uint32 p = src[k];
        int dl = p >> 24;
        int pos = atomicAdd(&cur[dl], 1);
        csr[pos] = (int)(p & 0xFFFFFF);
    }
}

// ---------- legacy build path ----------
__global__ void hist_kernel(const void* __restrict__ ei, int E, const int* __restrict__ flag,
                            int* __restrict__ counts) {
    int e = blockIdx.x * TPB + threadIdx.x;
    if (e >= E) return;
    bool i64 = (*flag != 0);
    atomicAdd(&counts[load_idx(ei, E + e, i64)], 1);
}

__global__ void fill_kernel(const void* __restrict__ ei, int E, const int* __restrict__ flag,
                            int* __restrict__ cursor, int* __restrict__ csr_src) {
    int e = blockIdx.x * TPB + threadIdx.x;
    if (e >= E) return;
    bool i64 = (*flag != 0);
    int s = load_idx(ei, e, i64);
    int d = load_idx(ei, E + e, i64);
    int pos = atomicAdd(&cursor[d], 1);
    csr_src[pos] = s;
}

// ---------- dis = rsqrt(deg) ----------
__global__ void dis_kernel(const int* __restrict__ counts, float* __restrict__ dis, int n) {
    int i = blockIdx.x * TPB + threadIdx.x;
    if (i < n) dis[i] = rsqrtf((float)(counts[i] + 1));
}

// ---------- scans ----------
__global__ void scan_block_kernel(const int* __restrict__ counts, int* __restrict__ excl,
                                  int* __restrict__ partials, int n) {
    __shared__ int tmp[TPB];
    int tid = threadIdx.x, gid = blockIdx.x * TPB + tid;
    int v = (gid < n) ? counts[gid] : 0;
    tmp[tid] = v;
    __syncthreads();
    for (int off = 1; off < TPB; off <<= 1) {
        int t = (tid >= off) ? tmp[tid - off] : 0;
        __syncthreads();
        tmp[tid] += t;
        __syncthreads();
    }
    if (gid < n) excl[gid] = tmp[tid] - v;
    if (tid == TPB - 1) partials[blockIdx.x] = tmp[TPB - 1];
}

__global__ void scan_partials_kernel(int* __restrict__ partials, int nb) {
    __shared__ int tmp[512];
    int tid = threadIdx.x;
    int v = (tid < nb) ? partials[tid] : 0;
    tmp[tid] = v;
    __syncthreads();
    for (int off = 1; off < 512; off <<= 1) {
        int t = (tid >= off) ? tmp[tid - off] : 0;
        __syncthreads();
        tmp[tid] += t;
        __syncthreads();
    }
    if (tid < nb) partials[tid] = tmp[tid] - v;
}

__global__ void add_offsets_kernel(int* __restrict__ excl, const int* __restrict__ partials,
                                   int* __restrict__ cursor, int n) {
    int i = blockIdx.x * TPB + threadIdx.x;
    if (i < n) {
        int v = excl[i] + partials[blockIdx.x];
        excl[i] = v;
        cursor[i] = v;
    }
}

// ---------- MFMA GEMM: out[r][:] = bf16( (X[r][:] @ W) * dis[r] ), K=128 ----------
// 4 waves/block, 16 rows/wave, mfma_f32_16x16x32_bf16 over 4 k-steps x C/16 col-tiles.
// W staged transposed in LDS as bf16, row padded +8 shorts: b128 read start-bank
// = 4*((col+g) mod 8) -> uniform over banks, minimum-cycle reads.
// A-frag: lane l holds row (l&15), k = (l>>4)*8 + j. C/D (m89): col=lane&15,
// row=(lane>>4)*4+reg.
template <int C, bool XBF>
__global__ __launch_bounds__(256) void gemm_mfma_kernel(
    const void* __restrict__ Xv, const float* __restrict__ W,
    const float* __restrict__ dis, ushort16* __restrict__ out, int M)
{
    constexpr int NB = C / 16;          // col tiles: 8 (C=128) or 4 (C=64)
    __shared__ ushort16 Wt[C][136];     // [col][k], 34 KB / 17 KB

    for (int i = threadIdx.x; i < 128 * C; i += 256) {
        int k = i / C, c = i % C;       // coalesced fp32 read of W[k][c]
        Wt[c][k] = f2bf(W[i]);
    }
    __syncthreads();

    int wid  = threadIdx.x >> 6;
    int lane = threadIdx.x & 63;
    int g    = lane >> 4;               // k-group 0..3
    int li   = lane & 15;

    int row = blockIdx.x * 64 + wid * 16 + li;
    int rc  = min(row, M - 1);

    frag_cd acc[NB];
#pragma unroll
    for (int i = 0; i < NB; ++i) acc[i] = (frag_cd)0.0f;

#pragma unroll
    for (int t = 0; t < 4; ++t) {
        frag_ab a;
        if (XBF) {
            const ushort16* xp = (const ushort16*)Xv + (size_t)rc * 128 + t * 32 + g * 8;
            a = *(const frag_ab*)xp;
        } else {
            const float* xp = (const float*)Xv + (size_t)rc * 128 + t * 32 + g * 8;
            float4 p = *(const float4*)xp;
            float4 q = *(const float4*)(xp + 4);
            a[0] = (short)f2bf(p.x); a[1] = (short)f2bf(p.y);
            a[2] = (short)f2bf(p.z); a[3] = (short)f2bf(p.w);
            a[4] = (short)f2bf(q.x); a[5] = (short)f2bf(q.y);
            a[6] = (short)f2bf(q.z); a[7] = (short)f2bf(q.w);
        }
#pragma unroll
        for (int cb = 0; cb < NB; ++cb) {
            frag_ab b = *(const frag_ab*)&Wt[cb * 16 + li][t * 32 + g * 8];
            acc[cb] = __builtin_amdgcn_mfma_f32_16x16x32_bf16(a, b, acc[cb], 0, 0, 0);
        }
    }

    int ro = blockIdx.x * 64 + wid * 16 + g * 4;
#pragma unroll
    for (int r = 0; r < 4; ++r) {
        int rr = ro + r;
        if (rr < M) {
            float dsc = dis[rr];
#pragma unroll
            for (int cb = 0; cb < NB; ++cb)
                out[(size_t)rr * C + cb * 16 + li] = f2bf(acc[cb][r] * dsc);
        }
    }
}

// ---------- aggregation C=128: wave per node, half-wave per edge (uint2/lane) ----------
__global__ __launch_bounds__(256) void agg128_kernel(
    const uint32* __restrict__ hs, const int* __restrict__ csr,
    const int* __restrict__ row_ptr, const int* __restrict__ counts,
    const float* __restrict__ dis, const float* __restrict__ b,
    uint32* __restrict__ out, int n)
{
    int wave = threadIdx.x >> 6;
    int lane = threadIdx.x & 63;
    int h    = lane >> 5;
    int sl   = lane & 31;
    int node = blockIdx.x * 4 + wave;
    if (node >= n) return;

    const uint2* hsv = (const uint2*)hs;
    float a0 = 0.f, a1 = 0.f, a2 = 0.f, a3 = 0.f;
    if (h == 0) {
        uint2 u = hsv[(size_t)node * 32 + sl];
        a0 = bflo(u.x); a1 = bfhi(u.x); a2 = bflo(u.y); a3 = bfhi(u.y);
    }

    int start = row_ptr[node];
    int end   = start + counts[node];
    int k = start;
    for (; k + 7 < end; k += 8) {
        int base = k + (h << 2);
        int s0 = csr[base], s1 = csr[base + 1], s2 = csr[base + 2], s3 = csr[base + 3];
        uint2 u0 = hsv[(size_t)s0 * 32 + sl];
        uint2 u1 = hsv[(size_t)s1 * 32 + sl];
        uint2 u2 = hsv[(size_t)s2 * 32 + sl];
        uint2 u3 = hsv[(size_t)s3 * 32 + sl];
        a0 += bflo(u0.x) + bflo(u1.x) + bflo(u2.x) + bflo(u3.x);
        a1 += bfhi(u0.x) + bfhi(u1.x) + bfhi(u2.x) + bfhi(u3.x);
        a2 += bflo(u0.y) + bflo(u1.y) + bflo(u2.y) + bflo(u3.y);
        a3 += bfhi(u0.y) + bfhi(u1.y) + bfhi(u2.y) + bfhi(u3.y);
    }
    for (; k + 3 < end; k += 4) {
        int base = k + (h << 1);
        int s0 = csr[base], s1 = csr[base + 1];
        uint2 u0 = hsv[(size_t)s0 * 32 + sl];
        uint2 u1 = hsv[(size_t)s1 * 32 + sl];
        a0 += bflo(u0.x) + bflo(u1.x);
        a1 += bfhi(u0.x) + bfhi(u1.x);
        a2 += bflo(u0.y) + bflo(u1.y);
        a3 += bfhi(u0.y) + bfhi(u1.y);
    }
    for (; k < end; k += 2) {
        int e = k + h;
        if (e < end) {
            uint2 u = hsv[(size_t)csr[e] * 32 + sl];
            a0 += bflo(u.x); a1 += bfhi(u.x); a2 += bflo(u.y); a3 += bfhi(u.y);
        }
    }

    a0 += __shfl_xor(a0, 32, 64);
    a1 += __shfl_xor(a1, 32, 64);
    a2 += __shfl_xor(a2, 32, 64);
    a3 += __shfl_xor(a3, 32, 64);

    if (h == 0) {
        float dsc = dis[node];
        float4 bb = ((const float4*)b)[sl];
        float v0 = fmaxf(a0 * dsc + bb.x, 0.0f);
        float v1 = fmaxf(a1 * dsc + bb.y, 0.0f);
        float v2 = fmaxf(a2 * dsc + bb.z, 0.0f);
        float v3 = fmaxf(a3 * dsc + bb.w, 0.0f);
        uint2 o; o.x = packbf(v0, v1); o.y = packbf(v2, v3);
        ((uint2*)out)[(size_t)node * 32 + sl] = o;
    }
}

// ---------- aggregation C=64: wave per node, quarter-wave per edge (uint2/lane) ----------
__global__ __launch_bounds__(256) void agg64_kernel(
    const uint32* __restrict__ hs, const int* __restrict__ csr,
    const int* __restrict__ row_ptr, const int* __restrict__ counts,
    const float* __restrict__ dis, const float* __restrict__ b,
    float* __restrict__ out, int n)
{
    int wave = threadIdx.x >> 6;
    int lane = threadIdx.x & 63;
    int q    = lane >> 4;
    int sl   = lane & 15;
    int node = blockIdx.x * 4 + wave;
    if (node >= n) return;

    const uint2* hsv = (const uint2*)hs;
    float a0 = 0.f, a1 = 0.f, a2 = 0.f, a3 = 0.f;
    if (q == 0) {
        uint2 u = hsv[(size_t)node * 16 + sl];
        a0 = bflo(u.x); a1 = bfhi(u.x); a2 = bflo(u.y); a3 = bfhi(u.y);
    }

    int start = row_ptr[node];
    int end   = start + counts[node];
    int k = start;
    for (; k + 7 < end; k += 8) {
        int base = k + (q << 1);
        int s0 = csr[base], s1 = csr[base + 1];
        uint2 u0 = hsv[(size_t)s0 * 16 + sl];
        uint2 u1 = hsv[(size_t)s1 * 16 + sl];
        a0 += bflo(u0.x) + bflo(u1.x);
        a1 += bfhi(u0.x) + bfhi(u1.x);
        a2 += bflo(u0.y) + bflo(u1.y);
        a3 += bfhi(u0.y) + bfhi(u1.y);
    }
    for (; k < end; k += 4) {
        int e = k + q;
        if (e < end) {
            uint2 u = hsv[(size_t)csr[e] * 16 + sl];
            a0 += bflo(u.x); a1 += bfhi(u.x); a2 += bflo(u.y); a3 += bfhi(u.y);
        }
    }

    a0 += __shfl_xor(a0, 16, 64);  a0 += __shfl_xor(a0, 32, 64);
    a1 += __shfl_xor(a1, 16, 64);  a1 += __shfl_xor(a1, 32, 64);
    a2 += __shfl_xor(a2, 16, 64);  a2 += __shfl_xor(a2, 32, 64);
    a3 += __shfl_xor(a3, 16, 64);  a3 += __shfl_xor(a3, 32, 64);

    if (q == 0) {
        float dsc = dis[node];
        float4 bb = ((const float4*)b)[sl];
        float4 o;
        o.x = 0.1f + 0.8f / (1.0f + __expf(-(a0 * dsc + bb.x)));
        o.y = 0.1f + 0.8f / (1.0f + __expf(-(a1 * dsc + bb.y)));
        o.z = 0.1f + 0.8f / (1.0f + __expf(-(a2 * dsc + bb.z)));
        o.w = 0.1f + 0.8f / (1.0f + __expf(-(a3 * dsc + bb.w)));
        ((float4*)out)[(size_t)node * 16 + sl] = o;
    }
}

extern "C" void kernel_launch(void* const* d_in, const int* in_sizes, int n_in,
                              void* d_out, int out_size, void* d_ws, size_t ws_size,
                              hipStream_t stream) {
    const float* x  = (const float*)d_in[0];
    const void*  ei = d_in[1];
    const float* W1 = (const float*)d_in[2];
    const float* b1 = (const float*)d_in[3];
    const float* W2 = (const float*)d_in[4];
    const float* b2 = (const float*)d_in[5];

    const int N = in_sizes[0] / IN_F;   // 100000
    const int E = in_sizes[1] / 2;      // 1600000

    const int nbuckets = (N + 255) >> 8;                 // 391
    const int bcap     = (int)(2 * ((long long)E / (nbuckets > 0 ? nbuckets : 1)) + 2048);
    const bool bucketed = (nbuckets <= MAXBK) && (N <= (1 << 24));

    auto alignup = [](size_t v) { return (v + 255) & ~(size_t)255; };
    char* w = (char*)d_ws;
    size_t off = 0;
    int*      flag     = (int*)(w + off);      off = alignup(off + 16);
    int*      counts   = (int*)(w + off);      off = alignup(off + (size_t)(N + MAXBK) * sizeof(int));
    int*      bcur     = counts + N;
    int*      cursor   = (int*)(w + off);      off = alignup(off + (size_t)N * sizeof(int));
    int*      row_ptr  = (int*)(w + off);      off = alignup(off + (size_t)N * sizeof(int));
    int*      partials = (int*)(w + off);      off = alignup(off + 512 * sizeof(int));
    float*    dis      = (float*)(w + off);    off = alignup(off + (size_t)N * sizeof(float));
    int*      csr      = (int*)(w + off);      off = alignup(off + (size_t)E * sizeof(int));
    uint32*   bbuf     = (uint32*)(w + off);   off = alignup(off + (size_t)nbuckets * bcap * sizeof(uint32));
    uint32*   A        = (uint32*)(w + off);   off = alignup(off + (size_t)N * HID * sizeof(ushort16));
    uint32*   B        = (uint32*)(w + off);   off = alignup(off + (size_t)N * HID * sizeof(ushort16));

    const int nbN = (N + TPB - 1) / TPB;   // 391
    const int nbE = (E + TPB - 1) / TPB;

    detect_i64_kernel<<<1, TPB, 0, stream>>>((const uint32*)ei, 256, flag);
    zero_int_kernel<<<(N + MAXBK + TPB - 1) / TPB, TPB, 0, stream>>>(counts, N + MAXBK);

    if (bucketed) {
        partition_kernel<<<(E + PT_TILE - 1) / PT_TILE, TPB, 0, stream>>>(
            ei, E, flag, nbuckets, bcap, counts, bcur, bbuf);
        dis_kernel<<<nbN, TPB, 0, stream>>>(counts, dis, N);
        scan_block_kernel<<<nbN, TPB, 0, stream>>>(counts, row_ptr, partials, N);
        scan_partials_kernel<<<1, 512, 0, stream>>>(partials, nbN);
        add_offsets_kernel<<<nbN, TPB, 0, stream>>>(row_ptr, partials, cursor, N);
        bucket_fill_kernel<<<nbuckets, TPB, 0, stream>>>(bbuf, bcur, row_ptr, csr, N, bcap);
    } else {
        hist_kernel<<<nbE, TPB, 0, stream>>>(ei, E, flag, counts);
        dis_kernel<<<nbN, TPB, 0, stream>>>(counts, dis, N);
        scan_block_kernel<<<nbN, TPB, 0, stream>>>(counts, row_ptr, partials, N);
        scan_partials_kernel<<<1, 512, 0, stream>>>(partials, nbN);
        add_offsets_kernel<<<nbN, TPB, 0, stream>>>(row_ptr, partials, cursor, N);
        fill_kernel<<<nbE, TPB, 0, stream>>>(ei, E, flag, cursor, csr);
    }

    const int gemmBlocks = (N + 63) / 64;

    // ---- layer 1: hs1 = bf16((x@W1)*dis) ; h1 = bf16(relu(dis*(hs1[d]+sum hs1[s])+b1))
    gemm_mfma_kernel<HID, false><<<gemmBlocks, TPB, 0, stream>>>(x, W1, dis, (ushort16*)A, N);
    agg128_kernel<<<(N + 3) / 4, TPB, 0, stream>>>(A, csr, row_ptr, counts, dis, b1, B, N);

    // ---- layer 2: hs2 = bf16((h1@W2)*dis) ; out = 0.1+0.8*sigmoid(dis*(hs2[d]+sum hs2[s])+b2)
    gemm_mfma_kernel<OUTF, true><<<gemmBlocks, TPB, 0, stream>>>(B, W2, dis, (ushort16*)A, N);
    agg64_kernel<<<(N + 3) / 4, TPB, 0, stream>>>(A, csr, row_ptr, counts, dis, b2, (float*)d_out, N);
}

// Round 8
// 213.310 us; speedup vs baseline: 20.0955x; 1.2161x over previous
//
#include <hip/hip_runtime.h>
#include <cstdint>
#include <cstddef>

#define IN_F 128
#define HID  128
#define OUTF 64

typedef unsigned int   uint32;
typedef unsigned short ushort16;

using frag_ab = __attribute__((ext_vector_type(8))) short;   // 8 bf16
using frag_cd = __attribute__((ext_vector_type(4))) float;   // 4 f32

static constexpr int TPB = 256;
static constexpr int PT_TILE = 2048;   // edges per partition block (R8: was 4096 -> occupancy fix)
static constexpr int PT_EPT  = 8;      // edges per thread
static constexpr int MAXBK   = 512;    // max buckets (N <= 131072) for bucketed path

// ---------- bf16 helpers (RNE) ----------
__device__ __forceinline__ float bflo(uint32 u) { return __uint_as_float(u << 16); }
__device__ __forceinline__ float bfhi(uint32 u) { return __uint_as_float(u & 0xFFFF0000u); }
__device__ __forceinline__ ushort16 f2bf(float f) {
    uint32 x = __float_as_uint(f);
    x = (x + 0x7FFFu + ((x >> 16) & 1u)) >> 16;
    return (ushort16)x;
}
__device__ __forceinline__ uint32 packbf(float a, float b) {
    return (uint32)f2bf(a) | ((uint32)f2bf(b) << 16);
}

// ---------- index dtype detection (int32 vs int64 layout) ----------
__global__ void detect_i64_kernel(const uint32* __restrict__ p, int npairs, int* __restrict__ flag) {
    __shared__ int anynz;
    if (threadIdx.x == 0) anynz = 0;
    __syncthreads();
    int i = threadIdx.x;
    if (i < npairs && p[2 * i + 1] != 0u) atomicOr(&anynz, 1);
    __syncthreads();
    if (threadIdx.x == 0) *flag = (anynz == 0) ? 1 : 0;
}

__device__ __forceinline__ int load_idx(const void* p, int i, bool i64) {
    return i64 ? (int)((const long long*)p)[i] : ((const int*)p)[i];
}

// ---------- zero ints ----------
__global__ void zero_int_kernel(int* __restrict__ p, int n) {
    int i = blockIdx.x * TPB + threadIdx.x;
    if (i < n) p[i] = 0;
}

// ---------- dst-bucket partition (NO global atomics; degree derived later) ----------
__global__ __launch_bounds__(256) void partition_kernel(
    const void* __restrict__ ei, int E, const int* __restrict__ flag,
    int nbuckets, int bcap,
    int* __restrict__ bcur, uint32* __restrict__ bbuf)
{
    __shared__ uint32   stash[PT_TILE];
    __shared__ ushort16 bidx[PT_TILE];
    __shared__ int hist[MAXBK];
    __shared__ int scanb[MAXBK];
    __shared__ int gbase[MAXBK];
    __shared__ int sum256[256];

    bool i64 = (*flag != 0);
    int tile0 = blockIdx.x * PT_TILE;
    int tid = threadIdx.x;

    for (int i = tid; i < nbuckets; i += 256) hist[i] = 0;
    __syncthreads();

    uint32 pck[PT_EPT];
    int    lofs[PT_EPT];
    short  bkt[PT_EPT];
#pragma unroll
    for (int j = 0; j < PT_EPT; ++j) {
        int e = tile0 + j * 256 + tid;
        if (e < E) {
            int s = load_idx(ei, e, i64);
            int d = load_idx(ei, E + e, i64);
            int b = d >> 8;
            pck[j]  = (uint32)s | ((uint32)(d & 255) << 24);
            bkt[j]  = (short)b;
            lofs[j] = atomicAdd(&hist[b], 1);
        } else bkt[j] = -1;
    }
    __syncthreads();

    for (int i = tid; i < nbuckets; i += 256)
        gbase[i] = hist[i] ? atomicAdd(&bcur[i], hist[i]) : 0;

    {   // exclusive scan of hist (2 elems/thread since MAXBK=512)
        int lt = tid * 2;
        int h0 = 0, h1 = 0;
        if (lt + 0 < nbuckets) h0 = hist[lt + 0];
        if (lt + 1 < nbuckets) h1 = hist[lt + 1];
        int lsum = h0 + h1;
        sum256[tid] = lsum;
        __syncthreads();
        for (int off = 1; off < 256; off <<= 1) {
            int t = (tid >= off) ? sum256[tid - off] : 0;
            __syncthreads();
            sum256[tid] += t;
            __syncthreads();
        }
        int excl = sum256[tid] - lsum;
        if (lt + 0 < nbuckets) scanb[lt + 0] = excl;
        if (lt + 1 < nbuckets) scanb[lt + 1] = excl + h0;
    }
    __syncthreads();

#pragma unroll
    for (int j = 0; j < PT_EPT; ++j) {
        if (bkt[j] >= 0) {
            int p = scanb[bkt[j]] + lofs[j];
            stash[p] = pck[j];
            bidx[p]  = (ushort16)bkt[j];
        }
    }
    __syncthreads();

    int total = min(PT_TILE, E - tile0);
    for (int k = tid; k < total; k += 256) {
        int b = bidx[k];
        int dst = gbase[b] + (k - scanb[b]);
        if (dst < bcap) bbuf[(size_t)b * bcap + dst] = stash[k];
    }
}

// ---------- per-bucket degree count + dis (coalesced writes; replaces global atomics) ----------
__global__ __launch_bounds__(256) void bucket_count_kernel(
    const uint32* __restrict__ bbuf, const int* __restrict__ bcur,
    int* __restrict__ counts, float* __restrict__ dis, int N, int bcap)
{
    __shared__ int h[256];
    int tid = threadIdx.x;
    h[tid] = 0;
    __syncthreads();
    int b = blockIdx.x;
    int cnt = min(bcur[b], bcap);
    const uint32* src = bbuf + (size_t)b * bcap;
    for (int k = tid; k < cnt; k += 256) atomicAdd(&h[src[k] >> 24], 1);
    __syncthreads();
    int node = (b << 8) + tid;
    if (node < N) {
        int c = h[tid];
        counts[node] = c;
        dis[node] = rsqrtf((float)(c + 1));   // +1 self-loop
    }
}

// ---------- pass B: per-bucket CSR fill ----------
__global__ __launch_bounds__(256) void bucket_fill_kernel(
    const uint32* __restrict__ bbuf, const int* __restrict__ bcur,
    const int* __restrict__ row_ptr, int* __restrict__ csr, int N, int bcap)
{
    __shared__ int cur[256];
    int b = blockIdx.x;
    int node = (b << 8) + threadIdx.x;
    cur[threadIdx.x] = (node < N) ? row_ptr[node] : 0;
    __syncthreads();
    int cnt = min(bcur[b], bcap);
    const uint32* src = bbuf + (size_t)b * bcap;
    for (int k = threadIdx.x; k < cnt; k += 256) {
        uint32 p = src[k];
        int dl = p >> 24;
        int pos = atomicAdd(&cur[dl], 1);
        csr[pos] = (int)(p & 0xFFFFFF);
    }
}

// ---------- legacy build path (N too large for bucketed path) ----------
__global__ void hist_kernel(const void* __restrict__ ei, int E, const int* __restrict__ flag,
                            int* __restrict__ counts) {
    int e = blockIdx.x * TPB + threadIdx.x;
    if (e >= E) return;
    bool i64 = (*flag != 0);
    atomicAdd(&counts[load_idx(ei, E + e, i64)], 1);
}

__global__ void fill_kernel(const void* __restrict__ ei, int E, const int* __restrict__ flag,
                            int* __restrict__ cursor, int* __restrict__ csr_src) {
    int e = blockIdx.x * TPB + threadIdx.x;
    if (e >= E) return;
    bool i64 = (*flag != 0);
    int s = load_idx(ei, e, i64);
    int d = load_idx(ei, E + e, i64);
    int pos = atomicAdd(&cursor[d], 1);
    csr_src[pos] = s;
}

__global__ void dis_kernel(const int* __restrict__ counts, float* __restrict__ dis, int n) {
    int i = blockIdx.x * TPB + threadIdx.x;
    if (i < n) dis[i] = rsqrtf((float)(counts[i] + 1));
}

// ---------- scans ----------
__global__ void scan_block_kernel(const int* __restrict__ counts, int* __restrict__ excl,
                                  int* __restrict__ partials, int n) {
    __shared__ int tmp[TPB];
    int tid = threadIdx.x, gid = blockIdx.x * TPB + tid;
    int v = (gid < n) ? counts[gid] : 0;
    tmp[tid] = v;
    __syncthreads();
    for (int off = 1; off < TPB; off <<= 1) {
        int t = (tid >= off) ? tmp[tid - off] : 0;
        __syncthreads();
        tmp[tid] += t;
        __syncthreads();
    }
    if (gid < n) excl[gid] = tmp[tid] - v;
    if (tid == TPB - 1) partials[blockIdx.x] = tmp[TPB - 1];
}

__global__ void scan_partials_kernel(int* __restrict__ partials, int nb) {
    __shared__ int tmp[512];
    int tid = threadIdx.x;
    int v = (tid < nb) ? partials[tid] : 0;
    tmp[tid] = v;
    __syncthreads();
    for (int off = 1; off < 512; off <<= 1) {
        int t = (tid >= off) ? tmp[tid - off] : 0;
        __syncthreads();
        tmp[tid] += t;
        __syncthreads();
    }
    if (tid < nb) partials[tid] = tmp[tid] - v;
}

__global__ void add_offsets_kernel(int* __restrict__ excl, const int* __restrict__ partials,
                                   int* __restrict__ cursor, int n) {
    int i = blockIdx.x * TPB + threadIdx.x;
    if (i < n) {
        int v = excl[i] + partials[blockIdx.x];
        excl[i] = v;
        cursor[i] = v;
    }
}

// ---------- MFMA GEMM: out[r][:] = bf16( (X[r][:] @ W) * dis[r] ), K=128 ----------
template <int C, bool XBF>
__global__ __launch_bounds__(256) void gemm_mfma_kernel(
    const void* __restrict__ Xv, const float* __restrict__ W,
    const float* __restrict__ dis, ushort16* __restrict__ out, int M)
{
    constexpr int NB = C / 16;
    __shared__ ushort16 Wt[C][136];

    for (int i = threadIdx.x; i < 128 * C; i += 256) {
        int k = i / C, c = i % C;
        Wt[c][k] = f2bf(W[i]);
    }
    __syncthreads();

    int wid  = threadIdx.x >> 6;
    int lane = threadIdx.x & 63;
    int g    = lane >> 4;
    int li   = lane & 15;

    int row = blockIdx.x * 64 + wid * 16 + li;
    int rc  = min(row, M - 1);

    frag_cd acc[NB];
#pragma unroll
    for (int i = 0; i < NB; ++i) acc[i] = (frag_cd)0.0f;

#pragma unroll
    for (int t = 0; t < 4; ++t) {
        frag_ab a;
        if (XBF) {
            const ushort16* xp = (const ushort16*)Xv + (size_t)rc * 128 + t * 32 + g * 8;
            a = *(const frag_ab*)xp;
        } else {
            const float* xp = (const float*)Xv + (size_t)rc * 128 + t * 32 + g * 8;
            float4 p = *(const float4*)xp;
            float4 q = *(const float4*)(xp + 4);
            a[0] = (short)f2bf(p.x); a[1] = (short)f2bf(p.y);
            a[2] = (short)f2bf(p.z); a[3] = (short)f2bf(p.w);
            a[4] = (short)f2bf(q.x); a[5] = (short)f2bf(q.y);
            a[6] = (short)f2bf(q.z); a[7] = (short)f2bf(q.w);
        }
#pragma unroll
        for (int cb = 0; cb < NB; ++cb) {
            frag_ab b = *(const frag_ab*)&Wt[cb * 16 + li][t * 32 + g * 8];
            acc[cb] = __builtin_amdgcn_mfma_f32_16x16x32_bf16(a, b, acc[cb], 0, 0, 0);
        }
    }

    int ro = blockIdx.x * 64 + wid * 16 + g * 4;
#pragma unroll
    for (int r = 0; r < 4; ++r) {
        int rr = ro + r;
        if (rr < M) {
            float dsc = dis[rr];
#pragma unroll
            for (int cb = 0; cb < NB; ++cb)
                out[(size_t)rr * C + cb * 16 + li] = f2bf(acc[cb][r] * dsc);
        }
    }
}

// ---------- aggregation C=128: wave per node, half-wave per edge (uint2/lane) ----------
__global__ __launch_bounds__(256) void agg128_kernel(
    const uint32* __restrict__ hs, const int* __restrict__ csr,
    const int* __restrict__ row_ptr, const int* __restrict__ counts,
    const float* __restrict__ dis, const float* __restrict__ b,
    uint32* __restrict__ out, int n)
{
    int wave = threadIdx.x >> 6;
    int lane = threadIdx.x & 63;
    int h    = lane >> 5;
    int sl   = lane & 31;
    int node = blockIdx.x * 4 + wave;
    if (node >= n) return;

    const uint2* hsv = (const uint2*)hs;
    float a0 = 0.f, a1 = 0.f, a2 = 0.f, a3 = 0.f;
    if (h == 0) {
        uint2 u = hsv[(size_t)node * 32 + sl];
        a0 = bflo(u.x); a1 = bfhi(u.x); a2 = bflo(u.y); a3 = bfhi(u.y);
    }

    int start = row_ptr[node];
    int end   = start + counts[node];
    int k = start;
    for (; k + 7 < end; k += 8) {
        int base = k + (h << 2);
        int s0 = csr[base], s1 = csr[base + 1], s2 = csr[base + 2], s3 = csr[base + 3];
        uint2 u0 = hsv[(size_t)s0 * 32 + sl];
        uint2 u1 = hsv[(size_t)s1 * 32 + sl];
        uint2 u2 = hsv[(size_t)s2 * 32 + sl];
        uint2 u3 = hsv[(size_t)s3 * 32 + sl];
        a0 += bflo(u0.x) + bflo(u1.x) + bflo(u2.x) + bflo(u3.x);
        a1 += bfhi(u0.x) + bfhi(u1.x) + bfhi(u2.x) + bfhi(u3.x);
        a2 += bflo(u0.y) + bflo(u1.y) + bflo(u2.y) + bflo(u3.y);
        a3 += bfhi(u0.y) + bfhi(u1.y) + bfhi(u2.y) + bfhi(u3.y);
    }
    for (; k + 3 < end; k += 4) {
        int base = k + (h << 1);
        int s0 = csr[base], s1 = csr[base + 1];
        uint2 u0 = hsv[(size_t)s0 * 32 + sl];
        uint2 u1 = hsv[(size_t)s1 * 32 + sl];
        a0 += bflo(u0.x) + bflo(u1.x);
        a1 += bfhi(u0.x) + bfhi(u1.x);
        a2 += bflo(u0.y) + bflo(u1.y);
        a3 += bfhi(u0.y) + bfhi(u1.y);
    }
    for (; k < end; k += 2) {
        int e = k + h;
        if (e < end) {
            uint2 u = hsv[(size_t)csr[e] * 32 + sl];
            a0 += bflo(u.x); a1 += bfhi(u.x); a2 += bflo(u.y); a3 += bfhi(u.y);
        }
    }

    a0 += __shfl_xor(a0, 32, 64);
    a1 += __shfl_xor(a1, 32, 64);
    a2 += __shfl_xor(a2, 32, 64);
    a3 += __shfl_xor(a3, 32, 64);

    if (h == 0) {
        float dsc = dis[node];
        float4 bb = ((const float4*)b)[sl];
        float v0 = fmaxf(a0 * dsc + bb.x, 0.0f);
        float v1 = fmaxf(a1 * dsc + bb.y, 0.0f);
        float v2 = fmaxf(a2 * dsc + bb.z, 0.0f);
        float v3 = fmaxf(a3 * dsc + bb.w, 0.0f);
        uint2 o; o.x = packbf(v0, v1); o.y = packbf(v2, v3);
        ((uint2*)out)[(size_t)node * 32 + sl] = o;
    }
}

// ---------- aggregation C=64: wave per node, quarter-wave per edge (uint2/lane) ----------
__global__ __launch_bounds__(256) void agg64_kernel(
    const uint32* __restrict__ hs, const int* __restrict__ csr,
    const int* __restrict__ row_ptr, const int* __restrict__ counts,
    const float* __restrict__ dis, const float* __restrict__ b,
    float* __restrict__ out, int n)
{
    int wave = threadIdx.x >> 6;
    int lane = threadIdx.x & 63;
    int q    = lane >> 4;
    int sl   = lane & 15;
    int node = blockIdx.x * 4 + wave;
    if (node >= n) return;

    const uint2* hsv = (const uint2*)hs;
    float a0 = 0.f, a1 = 0.f, a2 = 0.f, a3 = 0.f;
    if (q == 0) {
        uint2 u = hsv[(size_t)node * 16 + sl];
        a0 = bflo(u.x); a1 = bfhi(u.x); a2 = bflo(u.y); a3 = bfhi(u.y);
    }

    int start = row_ptr[node];
    int end   = start + counts[node];
    int k = start;
    for (; k + 7 < end; k += 8) {
        int base = k + (q << 1);
        int s0 = csr[base], s1 = csr[base + 1];
        uint2 u0 = hsv[(size_t)s0 * 16 + sl];
        uint2 u1 = hsv[(size_t)s1 * 16 + sl];
        a0 += bflo(u0.x) + bflo(u1.x);
        a1 += bfhi(u0.x) + bfhi(u1.x);
        a2 += bflo(u0.y) + bflo(u1.y);
        a3 += bfhi(u0.y) + bfhi(u1.y);
    }
    for (; k < end; k += 4) {
        int e = k + q;
        if (e < end) {
            uint2 u = hsv[(size_t)csr[e] * 16 + sl];
            a0 += bflo(u.x); a1 += bfhi(u.x); a2 += bflo(u.y); a3 += bfhi(u.y);
        }
    }

    a0 += __shfl_xor(a0, 16, 64);  a0 += __shfl_xor(a0, 32, 64);
    a1 += __shfl_xor(a1, 16, 64);  a1 += __shfl_xor(a1, 32, 64);
    a2 += __shfl_xor(a2, 16, 64);  a2 += __shfl_xor(a2, 32, 64);
    a3 += __shfl_xor(a3, 16, 64);  a3 += __shfl_xor(a3, 32, 64);

    if (q == 0) {
        float dsc = dis[node];
        float4 bb = ((const float4*)b)[sl];
        float4 o;
        o.x = 0.1f + 0.8f / (1.0f + __expf(-(a0 * dsc + bb.x)));
        o.y = 0.1f + 0.8f / (1.0f + __expf(-(a1 * dsc + bb.y)));
        o.z = 0.1f + 0.8f / (1.0f + __expf(-(a2 * dsc + bb.z)));
        o.w = 0.1f + 0.8f / (1.0f + __expf(-(a3 * dsc + bb.w)));
        ((float4*)out)[(size_t)node * 16 + sl] = o;
    }
}

extern "C" void kernel_launch(void* const* d_in, const int* in_sizes, int n_in,
                              void* d_out, int out_size, void* d_ws, size_t ws_size,
                              hipStream_t stream) {
    const float* x  = (const float*)d_in[0];
    const void*  ei = d_in[1];
    const float* W1 = (const float*)d_in[2];
    const float* b1 = (const float*)d_in[3];
    const float* W2 = (const float*)d_in[4];
    const float* b2 = (const float*)d_in[5];

    const int N = in_sizes[0] / IN_F;   // 100000
    const int E = in_sizes[1] / 2;      // 1600000

    const int nbuckets = (N + 255) >> 8;                 // 391
    const int bcap     = (int)(2 * ((long long)E / (nbuckets > 0 ? nbuckets : 1)) + 2048);
    const bool bucketed = (nbuckets <= MAXBK);

    auto alignup = [](size_t v) { return (v + 255) & ~(size_t)255; };
    char* w = (char*)d_ws;
    size_t off = 0;
    int*      flag     = (int*)(w + off);      off = alignup(off + 16);
    int*      counts   = (int*)(w + off);      off = alignup(off + (size_t)(N + MAXBK) * sizeof(int));
    int*      bcur     = counts + N;           // contiguous with counts; zeroed together (R2 lesson)
    int*      cursor   = (int*)(w + off);      off = alignup(off + (size_t)N * sizeof(int));
    int*      row_ptr  = (int*)(w + off);      off = alignup(off + (size_t)N * sizeof(int));
    int*      partials = (int*)(w + off);      off = alignup(off + 512 * sizeof(int));
    float*    dis      = (float*)(w + off);    off = alignup(off + (size_t)N * sizeof(float));
    int*      csr      = (int*)(w + off);      off = alignup(off + (size_t)E * sizeof(int));
    uint32*   bbuf     = (uint32*)(w + off);   off = alignup(off + (size_t)nbuckets * bcap * sizeof(uint32));
    uint32*   A        = (uint32*)(w + off);   off = alignup(off + (size_t)N * HID * sizeof(ushort16));
    uint32*   B        = (uint32*)(w + off);   off = alignup(off + (size_t)N * HID * sizeof(ushort16));

    const int nbN = (N + TPB - 1) / TPB;   // 391
    const int nbE = (E + TPB - 1) / TPB;

    detect_i64_kernel<<<1, TPB, 0, stream>>>((const uint32*)ei, 256, flag);
    zero_int_kernel<<<(N + MAXBK + TPB - 1) / TPB, TPB, 0, stream>>>(counts, N + MAXBK);

    if (bucketed) {
        partition_kernel<<<(E + PT_TILE - 1) / PT_TILE, TPB, 0, stream>>>(
            ei, E, flag, nbuckets, bcap, bcur, bbuf);
        bucket_count_kernel<<<nbuckets, TPB, 0, stream>>>(bbuf, bcur, counts, dis, N, bcap);
        scan_block_kernel<<<nbN, TPB, 0, stream>>>(counts, row_ptr, partials, N);
        scan_partials_kernel<<<1, 512, 0, stream>>>(partials, nbN);
        add_offsets_kernel<<<nbN, TPB, 0, stream>>>(row_ptr, partials, cursor, N);
        bucket_fill_kernel<<<nbuckets, TPB, 0, stream>>>(bbuf, bcur, row_ptr, csr, N, bcap);
    } else {
        hist_kernel<<<nbE, TPB, 0, stream>>>(ei, E, flag, counts);
        dis_kernel<<<nbN, TPB, 0, stream>>>(counts, dis, N);
        scan_block_kernel<<<nbN, TPB, 0, stream>>>(counts, row_ptr, partials, N);
        scan_partials_kernel<<<1, 512, 0, stream>>>(partials, nbN);
        add_offsets_kernel<<<nbN, TPB, 0, stream>>>(row_ptr, partials, cursor, N);
        fill_kernel<<<nbE, TPB, 0, stream>>>(ei, E, flag, cursor, csr);
    }

    const int gemmBlocks = (N + 63) / 64;

    // ---- layer 1: hs1 = bf16((x@W1)*dis) ; h1 = bf16(relu(dis*(hs1[d]+sum hs1[s])+b1))
    gemm_mfma_kernel<HID, false><<<gemmBlocks, TPB, 0, stream>>>(x, W1, dis, (ushort16*)A, N);
    agg128_kernel<<<(N + 3) / 4, TPB, 0, stream>>>(A, csr, row_ptr, counts, dis, b1, B, N);

    // ---- layer 2: hs2 = bf16((h1@W2)*dis) ; out = 0.1+0.8*sigmoid(dis*(hs2[d]+sum hs2[s])+b2)
    gemm_mfma_kernel<OUTF, true><<<gemmBlocks, TPB, 0, stream>>>(B, W2, dis, (ushort16*)A, N);
    agg64_kernel<<<(N + 3) / 4, TPB, 0, stream>>>(A, csr, row_ptr, counts, dis, b2, (float*)d_out, N);
}

// Round 9
// 209.735 us; speedup vs baseline: 20.4380x; 1.0170x over previous
//
#include <hip/hip_runtime.h>
#include <cstdint>
#include <cstddef>

#define IN_F 128
#define HID  128
#define OUTF 64

typedef unsigned int   uint32;
typedef unsigned short ushort16;

using frag_ab = __attribute__((ext_vector_type(8))) short;   // 8 bf16
using frag_cd = __attribute__((ext_vector_type(4))) float;   // 4 f32

static constexpr int TPB = 256;
static constexpr int PT_TILE = 2048;   // edges per partition block
static constexpr int PT_EPT  = 8;      // edges per thread
static constexpr int MAXBK   = 512;    // max buckets (N <= 131072) for bucketed path

// ---------- bf16 helpers (RNE) ----------
__device__ __forceinline__ float bflo(uint32 u) { return __uint_as_float(u << 16); }
__device__ __forceinline__ float bfhi(uint32 u) { return __uint_as_float(u & 0xFFFF0000u); }
__device__ __forceinline__ ushort16 f2bf(float f) {
    uint32 x = __float_as_uint(f);
    x = (x + 0x7FFFu + ((x >> 16) & 1u)) >> 16;
    return (ushort16)x;
}
__device__ __forceinline__ uint32 packbf(float a, float b) {
    return (uint32)f2bf(a) | ((uint32)f2bf(b) << 16);
}

// ---------- index dtype detection (int32 vs int64 layout) ----------
__global__ void detect_i64_kernel(const uint32* __restrict__ p, int npairs, int* __restrict__ flag) {
    __shared__ int anynz;
    if (threadIdx.x == 0) anynz = 0;
    __syncthreads();
    int i = threadIdx.x;
    if (i < npairs && p[2 * i + 1] != 0u) atomicOr(&anynz, 1);
    __syncthreads();
    if (threadIdx.x == 0) *flag = (anynz == 0) ? 1 : 0;
}

__device__ __forceinline__ int load_idx(const void* p, int i, bool i64) {
    return i64 ? (int)((const long long*)p)[i] : ((const int*)p)[i];
}

// ---------- dst-bucket partition (NO global atomics; degree derived later) ----------
__global__ __launch_bounds__(256) void partition_kernel(
    const void* __restrict__ ei, int E, const int* __restrict__ flag,
    int nbuckets, int bcap,
    int* __restrict__ bcur, uint32* __restrict__ bbuf)
{
    __shared__ uint32   stash[PT_TILE];
    __shared__ ushort16 bidx[PT_TILE];
    __shared__ int hist[MAXBK];
    __shared__ int scanb[MAXBK];
    __shared__ int gbase[MAXBK];
    __shared__ int sum256[256];

    bool i64 = (*flag != 0);
    int tile0 = blockIdx.x * PT_TILE;
    int tid = threadIdx.x;

    for (int i = tid; i < nbuckets; i += 256) hist[i] = 0;
    __syncthreads();

    uint32 pck[PT_EPT];
    int    lofs[PT_EPT];
    short  bkt[PT_EPT];
#pragma unroll
    for (int j = 0; j < PT_EPT; ++j) {
        int e = tile0 + j * 256 + tid;
        if (e < E) {
            int s = load_idx(ei, e, i64);
            int d = load_idx(ei, E + e, i64);
            int b = d >> 8;
            pck[j]  = (uint32)s | ((uint32)(d & 255) << 24);
            bkt[j]  = (short)b;
            lofs[j] = atomicAdd(&hist[b], 1);
        } else bkt[j] = -1;
    }
    __syncthreads();

    for (int i = tid; i < nbuckets; i += 256)
        gbase[i] = hist[i] ? atomicAdd(&bcur[i], hist[i]) : 0;

    {   // exclusive scan of hist (2 elems/thread since MAXBK=512)
        int lt = tid * 2;
        int h0 = 0, h1 = 0;
        if (lt + 0 < nbuckets) h0 = hist[lt + 0];
        if (lt + 1 < nbuckets) h1 = hist[lt + 1];
        int lsum = h0 + h1;
        sum256[tid] = lsum;
        __syncthreads();
        for (int off = 1; off < 256; off <<= 1) {
            int t = (tid >= off) ? sum256[tid - off] : 0;
            __syncthreads();
            sum256[tid] += t;
            __syncthreads();
        }
        int excl = sum256[tid] - lsum;
        if (lt + 0 < nbuckets) scanb[lt + 0] = excl;
        if (lt + 1 < nbuckets) scanb[lt + 1] = excl + h0;
    }
    __syncthreads();

#pragma unroll
    for (int j = 0; j < PT_EPT; ++j) {
        if (bkt[j] >= 0) {
            int p = scanb[bkt[j]] + lofs[j];
            stash[p] = pck[j];
            bidx[p]  = (ushort16)bkt[j];
        }
    }
    __syncthreads();

    int total = min(PT_TILE, E - tile0);
    for (int k = tid; k < total; k += 256) {
        int b = bidx[k];
        int dst = gbase[b] + (k - scanb[b]);
        if (dst < bcap) bbuf[(size_t)b * bcap + dst] = stash[k];
    }
}

// ---------- per-bucket degree count + dis ----------
__global__ __launch_bounds__(256) void bucket_count_kernel(
    const uint32* __restrict__ bbuf, const int* __restrict__ bcur,
    int* __restrict__ counts, float* __restrict__ dis, int N, int bcap)
{
    __shared__ int h[256];
    int tid = threadIdx.x;
    h[tid] = 0;
    __syncthreads();
    int b = blockIdx.x;
    int cnt = min(bcur[b], bcap);
    const uint32* src = bbuf + (size_t)b * bcap;
    for (int k = tid; k < cnt; k += 256) atomicAdd(&h[src[k] >> 24], 1);
    __syncthreads();
    int node = (b << 8) + tid;
    if (node < N) {
        int c = h[tid];
        counts[node] = c;
        dis[node] = rsqrtf((float)(c + 1));   // +1 self-loop
    }
}

// ---------- pass B: per-bucket CSR fill ----------
__global__ __launch_bounds__(256) void bucket_fill_kernel(
    const uint32* __restrict__ bbuf, const int* __restrict__ bcur,
    const int* __restrict__ row_ptr, int* __restrict__ csr, int N, int bcap)
{
    __shared__ int cur[256];
    int b = blockIdx.x;
    int node = (b << 8) + threadIdx.x;
    cur[threadIdx.x] = (node < N) ? row_ptr[node] : 0;
    __syncthreads();
    int cnt = min(bcur[b], bcap);
    const uint32* src = bbuf + (size_t)b * bcap;
    for (int k = threadIdx.x; k < cnt; k += 256) {
        uint32 p = src[k];
        int dl = p >> 24;
        int pos = atomicAdd(&cur[dl], 1);
        csr[pos] = (int)(p & 0xFFFFFF);
    }
}

// ---------- legacy build path (N too large for bucketed path) ----------
__global__ void hist_kernel(const void* __restrict__ ei, int E, const int* __restrict__ flag,
                            int* __restrict__ counts) {
    int e = blockIdx.x * TPB + threadIdx.x;
    if (e >= E) return;
    bool i64 = (*flag != 0);
    atomicAdd(&counts[load_idx(ei, E + e, i64)], 1);
}

__global__ void fill_kernel(const void* __restrict__ ei, int E, const int* __restrict__ flag,
                            int* __restrict__ cursor, int* __restrict__ csr_src) {
    int e = blockIdx.x * TPB + threadIdx.x;
    if (e >= E) return;
    bool i64 = (*flag != 0);
    int s = load_idx(ei, e, i64);
    int d = load_idx(ei, E + e, i64);
    int pos = atomicAdd(&cursor[d], 1);
    csr_src[pos] = s;
}

__global__ void dis_kernel(const int* __restrict__ counts, float* __restrict__ dis, int n) {
    int i = blockIdx.x * TPB + threadIdx.x;
    if (i < n) dis[i] = rsqrtf((float)(counts[i] + 1));
}

// ---------- scans ----------
__global__ void scan_block_kernel(const int* __restrict__ counts, int* __restrict__ excl,
                                  int* __restrict__ partials, int n) {
    __shared__ int tmp[TPB];
    int tid = threadIdx.x, gid = blockIdx.x * TPB + tid;
    int v = (gid < n) ? counts[gid] : 0;
    tmp[tid] = v;
    __syncthreads();
    for (int off = 1; off < TPB; off <<= 1) {
        int t = (tid >= off) ? tmp[tid - off] : 0;
        __syncthreads();
        tmp[tid] += t;
        __syncthreads();
    }
    if (gid < n) excl[gid] = tmp[tid] - v;
    if (tid == TPB - 1) partials[blockIdx.x] = tmp[TPB - 1];
}

__global__ void scan_partials_kernel(int* __restrict__ partials, int nb) {
    __shared__ int tmp[512];
    int tid = threadIdx.x;
    int v = (tid < nb) ? partials[tid] : 0;
    tmp[tid] = v;
    __syncthreads();
    for (int off = 1; off < 512; off <<= 1) {
        int t = (tid >= off) ? tmp[tid - off] : 0;
        __syncthreads();
        tmp[tid] += t;
        __syncthreads();
    }
    if (tid < nb) partials[tid] = tmp[tid] - v;
}

__global__ void add_offsets_kernel(int* __restrict__ excl, const int* __restrict__ partials,
                                   int* __restrict__ cursor, int n) {
    int i = blockIdx.x * TPB + threadIdx.x;
    if (i < n) {
        int v = excl[i] + partials[blockIdx.x];
        excl[i] = v;
        cursor[i] = v;
    }
}

// ---------- MFMA GEMM: out[r][:] = bf16( (X[r][:] @ W) * dis[r] ), K=128 ----------
template <int C, bool XBF>
__global__ __launch_bounds__(256) void gemm_mfma_kernel(
    const void* __restrict__ Xv, const float* __restrict__ W,
    const float* __restrict__ dis, ushort16* __restrict__ out, int M)
{
    constexpr int NB = C / 16;
    __shared__ ushort16 Wt[C][136];

    for (int i = threadIdx.x; i < 128 * C; i += 256) {
        int k = i / C, c = i % C;
        Wt[c][k] = f2bf(W[i]);
    }
    __syncthreads();

    int wid  = threadIdx.x >> 6;
    int lane = threadIdx.x & 63;
    int g    = lane >> 4;
    int li   = lane & 15;

    int row = blockIdx.x * 64 + wid * 16 + li;
    int rc  = min(row, M - 1);

    frag_cd acc[NB];
#pragma unroll
    for (int i = 0; i < NB; ++i) acc[i] = (frag_cd)0.0f;

#pragma unroll
    for (int t = 0; t < 4; ++t) {
        frag_ab a;
        if (XBF) {
            const ushort16* xp = (const ushort16*)Xv + (size_t)rc * 128 + t * 32 + g * 8;
            a = *(const frag_ab*)xp;
        } else {
            const float* xp = (const float*)Xv + (size_t)rc * 128 + t * 32 + g * 8;
            float4 p = *(const float4*)xp;
            float4 q = *(const float4*)(xp + 4);
            a[0] = (short)f2bf(p.x); a[1] = (short)f2bf(p.y);
            a[2] = (short)f2bf(p.z); a[3] = (short)f2bf(p.w);
            a[4] = (short)f2bf(q.x); a[5] = (short)f2bf(q.y);
            a[6] = (short)f2bf(q.z); a[7] = (short)f2bf(q.w);
        }
#pragma unroll
        for (int cb = 0; cb < NB; ++cb) {
            frag_ab b = *(const frag_ab*)&Wt[cb * 16 + li][t * 32 + g * 8];
            acc[cb] = __builtin_amdgcn_mfma_f32_16x16x32_bf16(a, b, acc[cb], 0, 0, 0);
        }
    }

    int ro = blockIdx.x * 64 + wid * 16 + g * 4;
#pragma unroll
    for (int r = 0; r < 4; ++r) {
        int rr = ro + r;
        if (rr < M) {
            float dsc = dis[rr];
#pragma unroll
            for (int cb = 0; cb < NB; ++cb)
                out[(size_t)rr * C + cb * 16 + li] = f2bf(acc[cb][r] * dsc);
        }
    }
}

// ---------- aggregation C=128: wave per node, QUARTER-wave per edge (uint4/lane) ----------
// 16 lanes x 16B = 256B row; 16 edges/wave-iter, 4 independent loads in flight/lane
// (4KB/wave in flight, 2x R8 -> MLP-depth fix for the latency-bound gather).
__global__ __launch_bounds__(256) void agg128_kernel(
    const uint32* __restrict__ hs, const int* __restrict__ csr,
    const int* __restrict__ row_ptr, const int* __restrict__ counts,
    const float* __restrict__ dis, const float* __restrict__ b,
    uint32* __restrict__ out, int n)
{
    int wave = threadIdx.x >> 6;
    int lane = threadIdx.x & 63;
    int g    = lane >> 4;        // quarter 0..3
    int sl   = lane & 15;
    int node = blockIdx.x * 4 + wave;
    if (node >= n) return;

    const uint4* hsv = (const uint4*)hs;   // row = 16 uint4 (128 bf16)
    float a0 = 0.f, a1 = 0.f, a2 = 0.f, a3 = 0.f,
          a4 = 0.f, a5 = 0.f, a6 = 0.f, a7 = 0.f;
    if (g == 0) {   // self-loop counted once
        uint4 u = hsv[(size_t)node * 16 + sl];
        a0 = bflo(u.x); a1 = bfhi(u.x); a2 = bflo(u.y); a3 = bfhi(u.y);
        a4 = bflo(u.z); a5 = bfhi(u.z); a6 = bflo(u.w); a7 = bfhi(u.w);
    }

    int start = row_ptr[node];
    int end   = start + counts[node];
    int k = start;
    for (; k + 15 < end; k += 16) {     // quarter g: 4 edges k+4g..k+4g+3
        int base = k + (g << 2);
        int s0 = csr[base], s1 = csr[base + 1], s2 = csr[base + 2], s3 = csr[base + 3];
        uint4 u0 = hsv[(size_t)s0 * 16 + sl];
        uint4 u1 = hsv[(size_t)s1 * 16 + sl];
        uint4 u2 = hsv[(size_t)s2 * 16 + sl];
        uint4 u3 = hsv[(size_t)s3 * 16 + sl];
        a0 += bflo(u0.x) + bflo(u1.x) + bflo(u2.x) + bflo(u3.x);
        a1 += bfhi(u0.x) + bfhi(u1.x) + bfhi(u2.x) + bfhi(u3.x);
        a2 += bflo(u0.y) + bflo(u1.y) + bflo(u2.y) + bflo(u3.y);
        a3 += bfhi(u0.y) + bfhi(u1.y) + bfhi(u2.y) + bfhi(u3.y);
        a4 += bflo(u0.z) + bflo(u1.z) + bflo(u2.z) + bflo(u3.z);
        a5 += bfhi(u0.z) + bfhi(u1.z) + bfhi(u2.z) + bfhi(u3.z);
        a6 += bflo(u0.w) + bflo(u1.w) + bflo(u2.w) + bflo(u3.w);
        a7 += bfhi(u0.w) + bfhi(u1.w) + bfhi(u2.w) + bfhi(u3.w);
    }
    for (; k + 7 < end; k += 8) {       // quarter g: 2 edges
        int base = k + (g << 1);
        int s0 = csr[base], s1 = csr[base + 1];
        uint4 u0 = hsv[(size_t)s0 * 16 + sl];
        uint4 u1 = hsv[(size_t)s1 * 16 + sl];
        a0 += bflo(u0.x) + bflo(u1.x);  a1 += bfhi(u0.x) + bfhi(u1.x);
        a2 += bflo(u0.y) + bflo(u1.y);  a3 += bfhi(u0.y) + bfhi(u1.y);
        a4 += bflo(u0.z) + bflo(u1.z);  a5 += bfhi(u0.z) + bfhi(u1.z);
        a6 += bflo(u0.w) + bflo(u1.w);  a7 += bfhi(u0.w) + bfhi(u1.w);
    }
    for (; k < end; k += 4) {           // 1-7 remaining, guarded
        int e = k + g;
        if (e < end) {
            uint4 u = hsv[(size_t)csr[e] * 16 + sl];
            a0 += bflo(u.x); a1 += bfhi(u.x); a2 += bflo(u.y); a3 += bfhi(u.y);
            a4 += bflo(u.z); a5 += bfhi(u.z); a6 += bflo(u.w); a7 += bfhi(u.w);
        }
    }

    a0 += __shfl_xor(a0, 16, 64); a0 += __shfl_xor(a0, 32, 64);
    a1 += __shfl_xor(a1, 16, 64); a1 += __shfl_xor(a1, 32, 64);
    a2 += __shfl_xor(a2, 16, 64); a2 += __shfl_xor(a2, 32, 64);
    a3 += __shfl_xor(a3, 16, 64); a3 += __shfl_xor(a3, 32, 64);
    a4 += __shfl_xor(a4, 16, 64); a4 += __shfl_xor(a4, 32, 64);
    a5 += __shfl_xor(a5, 16, 64); a5 += __shfl_xor(a5, 32, 64);
    a6 += __shfl_xor(a6, 16, 64); a6 += __shfl_xor(a6, 32, 64);
    a7 += __shfl_xor(a7, 16, 64); a7 += __shfl_xor(a7, 32, 64);

    if (g == 0) {
        float dsc = dis[node];
        float4 bb0 = ((const float4*)b)[sl * 2];
        float4 bb1 = ((const float4*)b)[sl * 2 + 1];
        float v0 = fmaxf(a0 * dsc + bb0.x, 0.0f);
        float v1 = fmaxf(a1 * dsc + bb0.y, 0.0f);
        float v2 = fmaxf(a2 * dsc + bb0.z, 0.0f);
        float v3 = fmaxf(a3 * dsc + bb0.w, 0.0f);
        float v4 = fmaxf(a4 * dsc + bb1.x, 0.0f);
        float v5 = fmaxf(a5 * dsc + bb1.y, 0.0f);
        float v6 = fmaxf(a6 * dsc + bb1.z, 0.0f);
        float v7 = fmaxf(a7 * dsc + bb1.w, 0.0f);
        uint4 o;
        o.x = packbf(v0, v1); o.y = packbf(v2, v3);
        o.z = packbf(v4, v5); o.w = packbf(v6, v7);
        ((uint4*)out)[(size_t)node * 16 + sl] = o;
    }
}

// ---------- aggregation C=64: wave per node, EIGHTH-wave per edge (uint4/lane) ----------
__global__ __launch_bounds__(256) void agg64_kernel(
    const uint32* __restrict__ hs, const int* __restrict__ csr,
    const int* __restrict__ row_ptr, const int* __restrict__ counts,
    const float* __restrict__ dis, const float* __restrict__ b,
    float* __restrict__ out, int n)
{
    int wave = threadIdx.x >> 6;
    int lane = threadIdx.x & 63;
    int g    = lane >> 3;        // eighth 0..7
    int sl   = lane & 7;
    int node = blockIdx.x * 4 + wave;
    if (node >= n) return;

    const uint4* hsv = (const uint4*)hs;   // row = 8 uint4 (64 bf16)
    float a0 = 0.f, a1 = 0.f, a2 = 0.f, a3 = 0.f,
          a4 = 0.f, a5 = 0.f, a6 = 0.f, a7 = 0.f;
    if (g == 0) {
        uint4 u = hsv[(size_t)node * 8 + sl];
        a0 = bflo(u.x); a1 = bfhi(u.x); a2 = bflo(u.y); a3 = bfhi(u.y);
        a4 = bflo(u.z); a5 = bfhi(u.z); a6 = bflo(u.w); a7 = bfhi(u.w);
    }

    int start = row_ptr[node];
    int end   = start + counts[node];
    int k = start;
    for (; k + 15 < end; k += 16) {     // eighth g: 2 edges k+2g, k+2g+1
        int base = k + (g << 1);
        int s0 = csr[base], s1 = csr[base + 1];
        uint4 u0 = hsv[(size_t)s0 * 8 + sl];
        uint4 u1 = hsv[(size_t)s1 * 8 + sl];
        a0 += bflo(u0.x) + bflo(u1.x);  a1 += bfhi(u0.x) + bfhi(u1.x);
        a2 += bflo(u0.y) + bflo(u1.y);  a3 += bfhi(u0.y) + bfhi(u1.y);
        a4 += bflo(u0.z) + bflo(u1.z);  a5 += bfhi(u0.z) + bfhi(u1.z);
        a6 += bflo(u0.w) + bflo(u1.w);  a7 += bfhi(u0.w) + bfhi(u1.w);
    }
    for (; k + 7 < end; k += 8) {       // eighth g: 1 edge, unguarded
        int e = k + g;
        uint4 u = hsv[(size_t)csr[e] * 8 + sl];
        a0 += bflo(u.x); a1 += bfhi(u.x); a2 += bflo(u.y); a3 += bfhi(u.y);
        a4 += bflo(u.z); a5 += bfhi(u.z); a6 += bflo(u.w); a7 += bfhi(u.w);
    }
    for (; k < end; k += 8) {           // 1-7 remaining, guarded
        int e = k + g;
        if (e < end) {
            uint4 u = hsv[(size_t)csr[e] * 8 + sl];
            a0 += bflo(u.x); a1 += bfhi(u.x); a2 += bflo(u.y); a3 += bfhi(u.y);
            a4 += bflo(u.z); a5 += bfhi(u.z); a6 += bflo(u.w); a7 += bfhi(u.w);
        }
    }

    a0 += __shfl_xor(a0, 8, 64); a0 += __shfl_xor(a0, 16, 64); a0 += __shfl_xor(a0, 32, 64);
    a1 += __shfl_xor(a1, 8, 64); a1 += __shfl_xor(a1, 16, 64); a1 += __shfl_xor(a1, 32, 64);
    a2 += __shfl_xor(a2, 8, 64); a2 += __shfl_xor(a2, 16, 64); a2 += __shfl_xor(a2, 32, 64);
    a3 += __shfl_xor(a3, 8, 64); a3 += __shfl_xor(a3, 16, 64); a3 += __shfl_xor(a3, 32, 64);
    a4 += __shfl_xor(a4, 8, 64); a4 += __shfl_xor(a4, 16, 64); a4 += __shfl_xor(a4, 32, 64);
    a5 += __shfl_xor(a5, 8, 64); a5 += __shfl_xor(a5, 16, 64); a5 += __shfl_xor(a5, 32, 64);
    a6 += __shfl_xor(a6, 8, 64); a6 += __shfl_xor(a6, 16, 64); a6 += __shfl_xor(a6, 32, 64);
    a7 += __shfl_xor(a7, 8, 64); a7 += __shfl_xor(a7, 16, 64); a7 += __shfl_xor(a7, 32, 64);

    if (g == 0) {
        float dsc = dis[node];
        float4 bb0 = ((const float4*)b)[sl * 2];
        float4 bb1 = ((const float4*)b)[sl * 2 + 1];
        float4 o0, o1;
        o0.x = 0.1f + 0.8f / (1.0f + __expf(-(a0 * dsc + bb0.x)));
        o0.y = 0.1f + 0.8f / (1.0f + __expf(-(a1 * dsc + bb0.y)));
        o0.z = 0.1f + 0.8f / (1.0f + __expf(-(a2 * dsc + bb0.z)));
        o0.w = 0.1f + 0.8f / (1.0f + __expf(-(a3 * dsc + bb0.w)));
        o1.x = 0.1f + 0.8f / (1.0f + __expf(-(a4 * dsc + bb1.x)));
        o1.y = 0.1f + 0.8f / (1.0f + __expf(-(a5 * dsc + bb1.y)));
        o1.z = 0.1f + 0.8f / (1.0f + __expf(-(a6 * dsc + bb1.z)));
        o1.w = 0.1f + 0.8f / (1.0f + __expf(-(a7 * dsc + bb1.w)));
        ((float4*)out)[(size_t)node * 16 + sl * 2]     = o0;
        ((float4*)out)[(size_t)node * 16 + sl * 2 + 1] = o1;
    }
}

extern "C" void kernel_launch(void* const* d_in, const int* in_sizes, int n_in,
                              void* d_out, int out_size, void* d_ws, size_t ws_size,
                              hipStream_t stream) {
    const float* x  = (const float*)d_in[0];
    const void*  ei = d_in[1];
    const float* W1 = (const float*)d_in[2];
    const float* b1 = (const float*)d_in[3];
    const float* W2 = (const float*)d_in[4];
    const float* b2 = (const float*)d_in[5];

    const int N = in_sizes[0] / IN_F;   // 100000
    const int E = in_sizes[1] / 2;      // 1600000

    const int nbuckets = (N + 255) >> 8;                 // 391
    const int bcap     = (int)(2 * ((long long)E / (nbuckets > 0 ? nbuckets : 1)) + 2048);
    const bool bucketed = (nbuckets <= MAXBK);

    auto alignup = [](size_t v) { return (v + 255) & ~(size_t)255; };
    char* w = (char*)d_ws;
    size_t off = 0;
    int*      flag     = (int*)(w + off);      off = alignup(off + 16);
    int*      counts   = (int*)(w + off);      off = alignup(off + (size_t)(N + MAXBK) * sizeof(int));
    int*      bcur     = counts + N;           // contiguous with counts; zeroed together (R2 lesson)
    int*      cursor   = (int*)(w + off);      off = alignup(off + (size_t)N * sizeof(int));
    int*      row_ptr  = (int*)(w + off);      off = alignup(off + (size_t)N * sizeof(int));
    int*      partials = (int*)(w + off);      off = alignup(off + 512 * sizeof(int));
    float*    dis      = (float*)(w + off);    off = alignup(off + (size_t)N * sizeof(float));
    int*      csr      = (int*)(w + off);      off = alignup(off + (size_t)E * sizeof(int));
    uint32*   bbuf     = (uint32*)(w + off);   off = alignup(off + (size_t)nbuckets * bcap * sizeof(uint32));
    uint32*   A        = (uint32*)(w + off);   off = alignup(off + (size_t)N * HID * sizeof(ushort16));
    uint32*   B        = (uint32*)(w + off);   off = alignup(off + (size_t)N * HID * sizeof(ushort16));

    const int nbN = (N + TPB - 1) / TPB;   // 391
    const int nbE = (E + TPB - 1) / TPB;

    detect_i64_kernel<<<1, TPB, 0, stream>>>((const uint32*)ei, 256, flag);
    hipMemsetAsync(counts, 0, (size_t)(N + MAXBK) * sizeof(int), stream);

    if (bucketed) {
        partition_kernel<<<(E + PT_TILE - 1) / PT_TILE, TPB, 0, stream>>>(
            ei, E, flag, nbuckets, bcap, bcur, bbuf);
        bucket_count_kernel<<<nbuckets, TPB, 0, stream>>>(bbuf, bcur, counts, dis, N, bcap);
        scan_block_kernel<<<nbN, TPB, 0, stream>>>(counts, row_ptr, partials, N);
        scan_partials_kernel<<<1, 512, 0, stream>>>(partials, nbN);
        add_offsets_kernel<<<nbN, TPB, 0, stream>>>(row_ptr, partials, cursor, N);
        bucket_fill_kernel<<<nbuckets, TPB, 0, stream>>>(bbuf, bcur, row_ptr, csr, N, bcap);
    } else {
        hist_kernel<<<nbE, TPB, 0, stream>>>(ei, E, flag, counts);
        dis_kernel<<<nbN, TPB, 0, stream>>>(counts, dis, N);
        scan_block_kernel<<<nbN, TPB, 0, stream>>>(counts, row_ptr, partials, N);
        scan_partials_kernel<<<1, 512, 0, stream>>>(partials, nbN);
        add_offsets_kernel<<<nbN, TPB, 0, stream>>>(row_ptr, partials, cursor, N);
        fill_kernel<<<nbE, TPB, 0, stream>>>(ei, E, flag, cursor, csr);
    }

    const int gemmBlocks = (N + 63) / 64;

    // ---- layer 1: hs1 = bf16((x@W1)*dis) ; h1 = bf16(relu(dis*(hs1[d]+sum hs1[s])+b1))
    gemm_mfma_kernel<HID, false><<<gemmBlocks, TPB, 0, stream>>>(x, W1, dis, (ushort16*)A, N);
    agg128_kernel<<<(N + 3) / 4, TPB, 0, stream>>>(A, csr, row_ptr, counts, dis, b1, B, N);

    // ---- layer 2: hs2 = bf16((h1@W2)*dis) ; out = 0.1+0.8*sigmoid(dis*(hs2[d]+sum hs2[s])+b2)
    gemm_mfma_kernel<OUTF, true><<<gemmBlocks, TPB, 0, stream>>>(B, W2, dis, (ushort16*)A, N);
    agg64_kernel<<<(N + 3) / 4, TPB, 0, stream>>>(A, csr, row_ptr, counts, dis, b2, (float*)d_out, N);
}

// Round 10
// 203.286 us; speedup vs baseline: 21.0864x; 1.0317x over previous
//
#include <hip/hip_runtime.h>
#include <cstdint>
#include <cstddef>

#define IN_F 128
#define HID  128
#define OUTF 64

typedef unsigned int   uint32;
typedef unsigned short ushort16;

using frag_ab = __attribute__((ext_vector_type(8))) short;   // 8 bf16
using frag_cd = __attribute__((ext_vector_type(4))) float;   // 4 f32

static constexpr int TPB = 256;
static constexpr int PT_TILE = 2048;   // edges per partition block
static constexpr int PT_EPT  = 8;      // edges per thread
static constexpr int MAXBK   = 512;    // max buckets (N <= 131072) for bucketed path
// mega1 shared: max(partition 19456 B, gemm Wt 128*136*2 = 34816 B)
static constexpr int MEGA_SMEM = 34816;

// ---------- bf16 helpers (RNE) ----------
__device__ __forceinline__ float bflo(uint32 u) { return __uint_as_float(u << 16); }
__device__ __forceinline__ float bfhi(uint32 u) { return __uint_as_float(u & 0xFFFF0000u); }
__device__ __forceinline__ ushort16 f2bf(float f) {
    uint32 x = __float_as_uint(f);
    x = (x + 0x7FFFu + ((x >> 16) & 1u)) >> 16;
    return (ushort16)x;
}
__device__ __forceinline__ uint32 packbf(float a, float b) {
    return (uint32)f2bf(a) | ((uint32)f2bf(b) << 16);
}

// ---------- index dtype detection ----------
__global__ void detect_i64_kernel(const uint32* __restrict__ p, int npairs, int* __restrict__ flag) {
    __shared__ int anynz;
    if (threadIdx.x == 0) anynz = 0;
    __syncthreads();
    int i = threadIdx.x;
    if (i < npairs && p[2 * i + 1] != 0u) atomicOr(&anynz, 1);
    __syncthreads();
    if (threadIdx.x == 0) *flag = (anynz == 0) ? 1 : 0;
}

__device__ __forceinline__ int load_idx(const void* p, int i, bool i64) {
    return i64 ? (int)((const long long*)p)[i] : ((const int*)p)[i];
}

// ---------- mega1: blocks [0,PB) = dst-bucket partition ; blocks [PB,..) = raw layer-1 GEMM ----------
__device__ void partition_body(char* smem, const void* __restrict__ ei, int E, bool i64,
                               int nbuckets, int bcap,
                               int* __restrict__ bcur, uint32* __restrict__ bbuf)
{
    uint32*   stash  = (uint32*)smem;                 // 8192 B
    ushort16* bidx   = (ushort16*)(smem + 8192);      // 4096 B
    int*      hist   = (int*)(smem + 12288);          // 2048 B
    int*      scanb  = (int*)(smem + 14336);          // 2048 B
    int*      gbase  = (int*)(smem + 16384);          // 2048 B
    int*      sum256 = (int*)(smem + 18432);          // 1024 B

    int tile0 = blockIdx.x * PT_TILE;
    int tid = threadIdx.x;

    for (int i = tid; i < nbuckets; i += 256) hist[i] = 0;
    __syncthreads();

    uint32 pck[PT_EPT];
    int    lofs[PT_EPT];
    short  bkt[PT_EPT];
#pragma unroll
    for (int j = 0; j < PT_EPT; ++j) {
        int e = tile0 + j * 256 + tid;
        if (e < E) {
            int s = load_idx(ei, e, i64);
            int d = load_idx(ei, E + e, i64);
            int b = d >> 8;
            pck[j]  = (uint32)s | ((uint32)(d & 255) << 24);
            bkt[j]  = (short)b;
            lofs[j] = atomicAdd(&hist[b], 1);
        } else bkt[j] = -1;
    }
    __syncthreads();

    for (int i = tid; i < nbuckets; i += 256)
        gbase[i] = hist[i] ? atomicAdd(&bcur[i], hist[i]) : 0;

    {   // exclusive scan of hist (2 elems/thread, MAXBK=512)
        int lt = tid * 2;
        int h0 = 0, h1 = 0;
        if (lt + 0 < nbuckets) h0 = hist[lt + 0];
        if (lt + 1 < nbuckets) h1 = hist[lt + 1];
        int lsum = h0 + h1;
        sum256[tid] = lsum;
        __syncthreads();
        for (int off = 1; off < 256; off <<= 1) {
            int t = (tid >= off) ? sum256[tid - off] : 0;
            __syncthreads();
            sum256[tid] += t;
            __syncthreads();
        }
        int excl = sum256[tid] - lsum;
        if (lt + 0 < nbuckets) scanb[lt + 0] = excl;
        if (lt + 1 < nbuckets) scanb[lt + 1] = excl + h0;
    }
    __syncthreads();

#pragma unroll
    for (int j = 0; j < PT_EPT; ++j) {
        if (bkt[j] >= 0) {
            int p = scanb[bkt[j]] + lofs[j];
            stash[p] = pck[j];
            bidx[p]  = (ushort16)bkt[j];
        }
    }
    __syncthreads();

    int total = min(PT_TILE, E - tile0);
    for (int k = tid; k < total; k += 256) {
        int b = bidx[k];
        int dst = gbase[b] + (k - scanb[b]);
        if (dst < bcap) bbuf[(size_t)b * bcap + dst] = stash[k];
    }
}

// raw layer-1 GEMM (C=128, fp32 input, NO dis scale): H[r][:] = bf16(X[r][:] @ W1)
__device__ void gemm1_body(char* smem, int gb, const float* __restrict__ X,
                           const float* __restrict__ W, ushort16* __restrict__ out, int M)
{
    typedef ushort16 WtRow[136];
    WtRow* Wt = (WtRow*)smem;           // [128][136]

    for (int i = threadIdx.x; i < 128 * 128; i += 256) {
        int k = i >> 7, c = i & 127;
        Wt[c][k] = f2bf(W[i]);
    }
    __syncthreads();

    int wid  = threadIdx.x >> 6;
    int lane = threadIdx.x & 63;
    int g    = lane >> 4;
    int li   = lane & 15;

    int row = gb * 64 + wid * 16 + li;
    int rc  = min(row, M - 1);

    frag_cd acc[8];
#pragma unroll
    for (int i = 0; i < 8; ++i) acc[i] = (frag_cd)0.0f;

#pragma unroll
    for (int t = 0; t < 4; ++t) {
        const float* xp = X + (size_t)rc * 128 + t * 32 + g * 8;
        float4 p = *(const float4*)xp;
        float4 q = *(const float4*)(xp + 4);
        frag_ab a;
        a[0] = (short)f2bf(p.x); a[1] = (short)f2bf(p.y);
        a[2] = (short)f2bf(p.z); a[3] = (short)f2bf(p.w);
        a[4] = (short)f2bf(q.x); a[5] = (short)f2bf(q.y);
        a[6] = (short)f2bf(q.z); a[7] = (short)f2bf(q.w);
#pragma unroll
        for (int cb = 0; cb < 8; ++cb) {
            frag_ab b = *(const frag_ab*)&Wt[cb * 16 + li][t * 32 + g * 8];
            acc[cb] = __builtin_amdgcn_mfma_f32_16x16x32_bf16(a, b, acc[cb], 0, 0, 0);
        }
    }

    int ro = gb * 64 + wid * 16 + g * 4;
#pragma unroll
    for (int r = 0; r < 4; ++r) {
        int rr = ro + r;
        if (rr < M) {
#pragma unroll
            for (int cb = 0; cb < 8; ++cb)
                out[(size_t)rr * 128 + cb * 16 + li] = f2bf(acc[cb][r]);
        }
    }
}

__global__ __launch_bounds__(256) void mega1_kernel(
    const void* __restrict__ ei, int E, const int* __restrict__ flag,
    int nbuckets, int bcap, int* __restrict__ bcur, uint32* __restrict__ bbuf,
    const float* __restrict__ X, const float* __restrict__ W1,
    ushort16* __restrict__ H, int M, int PB)
{
    __shared__ char smem[MEGA_SMEM];
    if ((int)blockIdx.x < PB) {
        partition_body(smem, ei, E, (*flag != 0), nbuckets, bcap, bcur, bbuf);
    } else {
        gemm1_body(smem, blockIdx.x - PB, X, W1, H, M);
    }
}

// ---------- 1-block exclusive scan of bucket totals -> bbase ----------
__global__ void bucket_base_kernel(const int* __restrict__ bcur, int* __restrict__ bbase,
                                   int nbuckets, int bcap) {
    __shared__ int tmp[512];
    int tid = threadIdx.x;
    int v = (tid < nbuckets) ? min(bcur[tid], bcap) : 0;
    tmp[tid] = v;
    __syncthreads();
    for (int off = 1; off < 512; off <<= 1) {
        int t = (tid >= off) ? tmp[tid - off] : 0;
        __syncthreads();
        tmp[tid] += t;
        __syncthreads();
    }
    if (tid < nbuckets) bbase[tid] = tmp[tid] - v;   // exclusive
}

// ---------- per-bucket: degree + dis + row_ptr (local LDS scan, no global scan) ----------
__global__ __launch_bounds__(256) void bucket_count2_kernel(
    const uint32* __restrict__ bbuf, const int* __restrict__ bcur, const int* __restrict__ bbase,
    int* __restrict__ counts, float* __restrict__ dis, int* __restrict__ row_ptr,
    int N, int bcap)
{
    __shared__ int h[256];
    __shared__ int sc[256];
    int tid = threadIdx.x;
    h[tid] = 0;
    __syncthreads();
    int b = blockIdx.x;
    int cnt = min(bcur[b], bcap);
    const uint32* src = bbuf + (size_t)b * bcap;
    for (int k = tid; k < cnt; k += 256) atomicAdd(&h[src[k] >> 24], 1);
    __syncthreads();
    int v = h[tid];
    sc[tid] = v;
    __syncthreads();
    for (int off = 1; off < 256; off <<= 1) {
        int t = (tid >= off) ? sc[tid - off] : 0;
        __syncthreads();
        sc[tid] += t;
        __syncthreads();
    }
    int node = (b << 8) + tid;
    if (node < N) {
        counts[node]  = v;
        dis[node]     = rsqrtf((float)(v + 1));      // +1 self-loop
        row_ptr[node] = bbase[b] + sc[tid] - v;      // exclusive within bucket
    }
}

// ---------- per-bucket CSR fill ----------
__global__ __launch_bounds__(256) void bucket_fill_kernel(
    const uint32* __restrict__ bbuf, const int* __restrict__ bcur,
    const int* __restrict__ row_ptr, int* __restrict__ csr, int N, int bcap)
{
    __shared__ int cur[256];
    int b = blockIdx.x;
    int node = (b << 8) + threadIdx.x;
    cur[threadIdx.x] = (node < N) ? row_ptr[node] : 0;
    __syncthreads();
    int cnt = min(bcur[b], bcap);
    const uint32* src = bbuf + (size_t)b * bcap;
    for (int k = threadIdx.x; k < cnt; k += 256) {
        uint32 p = src[k];
        int dl = p >> 24;
        int pos = atomicAdd(&cur[dl], 1);
        csr[pos] = (int)(p & 0xFFFFFF);
    }
}

// ---------- legacy build path (N too large for bucketed path) ----------
__global__ void hist_kernel(const void* __restrict__ ei, int E, const int* __restrict__ flag,
                            int* __restrict__ counts) {
    int e = blockIdx.x * TPB + threadIdx.x;
    if (e >= E) return;
    bool i64 = (*flag != 0);
    atomicAdd(&counts[load_idx(ei, E + e, i64)], 1);
}

__global__ void fill_kernel(const void* __restrict__ ei, int E, const int* __restrict__ flag,
                            int* __restrict__ cursor, int* __restrict__ csr_src) {
    int e = blockIdx.x * TPB + threadIdx.x;
    if (e >= E) return;
    bool i64 = (*flag != 0);
    int s = load_idx(ei, e, i64);
    int d = load_idx(ei, E + e, i64);
    int pos = atomicAdd(&cursor[d], 1);
    csr_src[pos] = s;
}

__global__ void dis_kernel(const int* __restrict__ counts, float* __restrict__ dis, int n) {
    int i = blockIdx.x * TPB + threadIdx.x;
    if (i < n) dis[i] = rsqrtf((float)(counts[i] + 1));
}

__global__ void scan_block_kernel(const int* __restrict__ counts, int* __restrict__ excl,
                                  int* __restrict__ partials, int n) {
    __shared__ int tmp[TPB];
    int tid = threadIdx.x, gid = blockIdx.x * TPB + tid;
    int v = (gid < n) ? counts[gid] : 0;
    tmp[tid] = v;
    __syncthreads();
    for (int off = 1; off < TPB; off <<= 1) {
        int t = (tid >= off) ? tmp[tid - off] : 0;
        __syncthreads();
        tmp[tid] += t;
        __syncthreads();
    }
    if (gid < n) excl[gid] = tmp[tid] - v;
    if (tid == TPB - 1) partials[blockIdx.x] = tmp[TPB - 1];
}

__global__ void scan_partials_kernel(int* __restrict__ partials, int nb) {
    __shared__ int tmp[512];
    int tid = threadIdx.x;
    int v = (tid < nb) ? partials[tid] : 0;
    tmp[tid] = v;
    __syncthreads();
    for (int off = 1; off < 512; off <<= 1) {
        int t = (tid >= off) ? tmp[tid - off] : 0;
        __syncthreads();
        tmp[tid] += t;
        __syncthreads();
    }
    if (tid < nb) partials[tid] = tmp[tid] - v;
}

__global__ void add_offsets_kernel(int* __restrict__ excl, const int* __restrict__ partials,
                                   int* __restrict__ cursor, int n) {
    int i = blockIdx.x * TPB + threadIdx.x;
    if (i < n) {
        int v = excl[i] + partials[blockIdx.x];
        excl[i] = v;
        cursor[i] = v;
    }
}

// ---------- MFMA GEMM (standalone): out[r][:] = bf16( (X@W)[r] * (SCALE? dis[r] : 1) ) ----------
template <int C, bool XBF, bool SCALE>
__global__ __launch_bounds__(256) void gemm_mfma_kernel(
    const void* __restrict__ Xv, const float* __restrict__ W,
    const float* __restrict__ dis, ushort16* __restrict__ out, int M)
{
    constexpr int NB = C / 16;
    __shared__ ushort16 Wt[C][136];

    for (int i = threadIdx.x; i < 128 * C; i += 256) {
        int k = i / C, c = i % C;
        Wt[c][k] = f2bf(W[i]);
    }
    __syncthreads();

    int wid  = threadIdx.x >> 6;
    int lane = threadIdx.x & 63;
    int g    = lane >> 4;
    int li   = lane & 15;

    int row = blockIdx.x * 64 + wid * 16 + li;
    int rc  = min(row, M - 1);

    frag_cd acc[NB];
#pragma unroll
    for (int i = 0; i < NB; ++i) acc[i] = (frag_cd)0.0f;

#pragma unroll
    for (int t = 0; t < 4; ++t) {
        frag_ab a;
        if (XBF) {
            const ushort16* xp = (const ushort16*)Xv + (size_t)rc * 128 + t * 32 + g * 8;
            a = *(const frag_ab*)xp;
        } else {
            const float* xp = (const float*)Xv + (size_t)rc * 128 + t * 32 + g * 8;
            float4 p = *(const float4*)xp;
            float4 q = *(const float4*)(xp + 4);
            a[0] = (short)f2bf(p.x); a[1] = (short)f2bf(p.y);
            a[2] = (short)f2bf(p.z); a[3] = (short)f2bf(p.w);
            a[4] = (short)f2bf(q.x); a[5] = (short)f2bf(q.y);
            a[6] = (short)f2bf(q.z); a[7] = (short)f2bf(q.w);
        }
#pragma unroll
        for (int cb = 0; cb < NB; ++cb) {
            frag_ab b = *(const frag_ab*)&Wt[cb * 16 + li][t * 32 + g * 8];
            acc[cb] = __builtin_amdgcn_mfma_f32_16x16x32_bf16(a, b, acc[cb], 0, 0, 0);
        }
    }

    int ro = blockIdx.x * 64 + wid * 16 + g * 4;
#pragma unroll
    for (int r = 0; r < 4; ++r) {
        int rr = ro + r;
        if (rr < M) {
            float dsc = SCALE ? dis[rr] : 1.0f;
#pragma unroll
            for (int cb = 0; cb < NB; ++cb)
                out[(size_t)rr * C + cb * 16 + li] = f2bf(acc[cb][r] * dsc);
        }
    }
}

#define ACC8(u, d) \
    a0 = fmaf(d, bflo(u.x), a0); a1 = fmaf(d, bfhi(u.x), a1); \
    a2 = fmaf(d, bflo(u.y), a2); a3 = fmaf(d, bfhi(u.y), a3); \
    a4 = fmaf(d, bflo(u.z), a4); a5 = fmaf(d, bfhi(u.z), a5); \
    a6 = fmaf(d, bflo(u.w), a6); a7 = fmaf(d, bfhi(u.w), a7);

// ---------- aggregation C=128 (raw h in, dis[s] folded in gather) ----------
// out[d] = relu( dis[d]*( dis[d]*h[d] + sum dis[s]*h[s] ) + b )
__global__ __launch_bounds__(256) void agg128_kernel(
    const uint32* __restrict__ hs, const int* __restrict__ csr,
    const int* __restrict__ row_ptr, const int* __restrict__ counts,
    const float* __restrict__ dis, const float* __restrict__ b,
    uint32* __restrict__ out, int n)
{
    int wave = threadIdx.x >> 6;
    int lane = threadIdx.x & 63;
    int g    = lane >> 4;        // quarter 0..3
    int sl   = lane & 15;
    int node = blockIdx.x * 4 + wave;
    if (node >= n) return;

    const uint4* hsv = (const uint4*)hs;   // row = 16 uint4 (128 bf16)
    float dsc = dis[node];
    float a0 = 0.f, a1 = 0.f, a2 = 0.f, a3 = 0.f,
          a4 = 0.f, a5 = 0.f, a6 = 0.f, a7 = 0.f;
    if (g == 0) {   // self-loop: dis[d]*h[d]
        uint4 u = hsv[(size_t)node * 16 + sl];
        ACC8(u, dsc);
    }

    int start = row_ptr[node];
    int end   = start + counts[node];
    int k = start;
    for (; k + 15 < end; k += 16) {     // quarter g: 4 edges
        int base = k + (g << 2);
        int s0 = csr[base], s1 = csr[base + 1], s2 = csr[base + 2], s3 = csr[base + 3];
        float d0 = dis[s0], d1 = dis[s1], d2 = dis[s2], d3 = dis[s3];
        uint4 u0 = hsv[(size_t)s0 * 16 + sl];
        uint4 u1 = hsv[(size_t)s1 * 16 + sl];
        uint4 u2 = hsv[(size_t)s2 * 16 + sl];
        uint4 u3 = hsv[(size_t)s3 * 16 + sl];
        ACC8(u0, d0); ACC8(u1, d1); ACC8(u2, d2); ACC8(u3, d3);
    }
    for (; k + 7 < end; k += 8) {       // quarter g: 2 edges
        int base = k + (g << 1);
        int s0 = csr[base], s1 = csr[base + 1];
        float d0 = dis[s0], d1 = dis[s1];
        uint4 u0 = hsv[(size_t)s0 * 16 + sl];
        uint4 u1 = hsv[(size_t)s1 * 16 + sl];
        ACC8(u0, d0); ACC8(u1, d1);
    }
    for (; k < end; k += 4) {           // 1-3 remaining, guarded
        int e = k + g;
        if (e < end) {
            int s0 = csr[e];
            float d0 = dis[s0];
            uint4 u = hsv[(size_t)s0 * 16 + sl];
            ACC8(u, d0);
        }
    }

    a0 += __shfl_xor(a0, 16, 64); a0 += __shfl_xor(a0, 32, 64);
    a1 += __shfl_xor(a1, 16, 64); a1 += __shfl_xor(a1, 32, 64);
    a2 += __shfl_xor(a2, 16, 64); a2 += __shfl_xor(a2, 32, 64);
    a3 += __shfl_xor(a3, 16, 64); a3 += __shfl_xor(a3, 32, 64);
    a4 += __shfl_xor(a4, 16, 64); a4 += __shfl_xor(a4, 32, 64);
    a5 += __shfl_xor(a5, 16, 64); a5 += __shfl_xor(a5, 32, 64);
    a6 += __shfl_xor(a6, 16, 64); a6 += __shfl_xor(a6, 32, 64);
    a7 += __shfl_xor(a7, 16, 64); a7 += __shfl_xor(a7, 32, 64);

    if (g == 0) {
        float4 bb0 = ((const float4*)b)[sl * 2];
        float4 bb1 = ((const float4*)b)[sl * 2 + 1];
        float v0 = fmaxf(a0 * dsc + bb0.x, 0.0f);
        float v1 = fmaxf(a1 * dsc + bb0.y, 0.0f);
        float v2 = fmaxf(a2 * dsc + bb0.z, 0.0f);
        float v3 = fmaxf(a3 * dsc + bb0.w, 0.0f);
        float v4 = fmaxf(a4 * dsc + bb1.x, 0.0f);
        float v5 = fmaxf(a5 * dsc + bb1.y, 0.0f);
        float v6 = fmaxf(a6 * dsc + bb1.z, 0.0f);
        float v7 = fmaxf(a7 * dsc + bb1.w, 0.0f);
        uint4 o;
        o.x = packbf(v0, v1); o.y = packbf(v2, v3);
        o.z = packbf(v4, v5); o.w = packbf(v6, v7);
        ((uint4*)out)[(size_t)node * 16 + sl] = o;
    }
}

// ---------- aggregation C=64 (hs2 has dis folded by gemm2), eighth-wave per edge ----------
__global__ __launch_bounds__(256) void agg64_kernel(
    const uint32* __restrict__ hs, const int* __restrict__ csr,
    const int* __restrict__ row_ptr, const int* __restrict__ counts,
    const float* __restrict__ dis, const float* __restrict__ b,
    float* __restrict__ out, int n)
{
    int wave = threadIdx.x >> 6;
    int lane = threadIdx.x & 63;
    int g    = lane >> 3;        // eighth 0..7
    int sl   = lane & 7;
    int node = blockIdx.x * 4 + wave;
    if (node >= n) return;

    const uint4* hsv = (const uint4*)hs;   // row = 8 uint4 (64 bf16)
    float a0 = 0.f, a1 = 0.f, a2 = 0.f, a3 = 0.f,
          a4 = 0.f, a5 = 0.f, a6 = 0.f, a7 = 0.f;
    if (g == 0) {
        uint4 u = hsv[(size_t)node * 8 + sl];
        ACC8(u, 1.0f);
    }

    int start = row_ptr[node];
    int end   = start + counts[node];
    int k = start;
    for (; k + 15 < end; k += 16) {
        int base = k + (g << 1);
        int s0 = csr[base], s1 = csr[base + 1];
        uint4 u0 = hsv[(size_t)s0 * 8 + sl];
        uint4 u1 = hsv[(size_t)s1 * 8 + sl];
        ACC8(u0, 1.0f); ACC8(u1, 1.0f);
    }
    for (; k + 7 < end; k += 8) {
        int e = k + g;
        uint4 u = hsv[(size_t)csr[e] * 8 + sl];
        ACC8(u, 1.0f);
    }
    for (; k < end; k += 8) {
        int e = k + g;
        if (e < end) {
            uint4 u = hsv[(size_t)csr[e] * 8 + sl];
            ACC8(u, 1.0f);
        }
    }

    a0 += __shfl_xor(a0, 8, 64); a0 += __shfl_xor(a0, 16, 64); a0 += __shfl_xor(a0, 32, 64);
    a1 += __shfl_xor(a1, 8, 64); a1 += __shfl_xor(a1, 16, 64); a1 += __shfl_xor(a1, 32, 64);
    a2 += __shfl_xor(a2, 8, 64); a2 += __shfl_xor(a2, 16, 64); a2 += __shfl_xor(a2, 32, 64);
    a3 += __shfl_xor(a3, 8, 64); a3 += __shfl_xor(a3, 16, 64); a3 += __shfl_xor(a3, 32, 64);
    a4 += __shfl_xor(a4, 8, 64); a4 += __shfl_xor(a4, 16, 64); a4 += __shfl_xor(a4, 32, 64);
    a5 += __shfl_xor(a5, 8, 64); a5 += __shfl_xor(a5, 16, 64); a5 += __shfl_xor(a5, 32, 64);
    a6 += __shfl_xor(a6, 8, 64); a6 += __shfl_xor(a6, 16, 64); a6 += __shfl_xor(a6, 32, 64);
    a7 += __shfl_xor(a7, 8, 64); a7 += __shfl_xor(a7, 16, 64); a7 += __shfl_xor(a7, 32, 64);

    if (g == 0) {
        float dsc = dis[node];
        float4 bb0 = ((const float4*)b)[sl * 2];
        float4 bb1 = ((const float4*)b)[sl * 2 + 1];
        float4 o0, o1;
        o0.x = 0.1f + 0.8f / (1.0f + __expf(-(a0 * dsc + bb0.x)));
        o0.y = 0.1f + 0.8f / (1.0f + __expf(-(a1 * dsc + bb0.y)));
        o0.z = 0.1f + 0.8f / (1.0f + __expf(-(a2 * dsc + bb0.z)));
        o0.w = 0.1f + 0.8f / (1.0f + __expf(-(a3 * dsc + bb0.w)));
        o1.x = 0.1f + 0.8f / (1.0f + __expf(-(a4 * dsc + bb1.x)));
        o1.y = 0.1f + 0.8f / (1.0f + __expf(-(a5 * dsc + bb1.y)));
        o1.z = 0.1f + 0.8f / (1.0f + __expf(-(a6 * dsc + bb1.z)));
        o1.w = 0.1f + 0.8f / (1.0f + __expf(-(a7 * dsc + bb1.w)));
        ((float4*)out)[(size_t)node * 16 + sl * 2]     = o0;
        ((float4*)out)[(size_t)node * 16 + sl * 2 + 1] = o1;
    }
}

extern "C" void kernel_launch(void* const* d_in, const int* in_sizes, int n_in,
                              void* d_out, int out_size, void* d_ws, size_t ws_size,
                              hipStream_t stream) {
    const float* x  = (const float*)d_in[0];
    const void*  ei = d_in[1];
    const float* W1 = (const float*)d_in[2];
    const float* b1 = (const float*)d_in[3];
    const float* W2 = (const float*)d_in[4];
    const float* b2 = (const float*)d_in[5];

    const int N = in_sizes[0] / IN_F;   // 100000
    const int E = in_sizes[1] / 2;      // 1600000

    const int nbuckets = (N + 255) >> 8;                 // 391
    const int bcap     = (int)(2 * ((long long)E / (nbuckets > 0 ? nbuckets : 1)) + 2048);
    const bool bucketed = (nbuckets <= MAXBK);

    auto alignup = [](size_t v) { return (v + 255) & ~(size_t)255; };
    char* w = (char*)d_ws;
    size_t off = 0;
    int*      flag     = (int*)(w + off);      off = alignup(off + 16);
    int*      counts   = (int*)(w + off);      off = alignup(off + (size_t)(N + MAXBK) * sizeof(int));
    int*      bcur     = counts + N;           // contiguous with counts (R2 lesson)
    int*      bbase    = (int*)(w + off);      off = alignup(off + MAXBK * sizeof(int));
    int*      cursor   = (int*)(w + off);      off = alignup(off + (size_t)N * sizeof(int));
    int*      row_ptr  = (int*)(w + off);      off = alignup(off + (size_t)N * sizeof(int));
    int*      partials = (int*)(w + off);      off = alignup(off + 512 * sizeof(int));
    float*    dis      = (float*)(w + off);    off = alignup(off + (size_t)N * sizeof(float));
    int*      csr      = (int*)(w + off);      off = alignup(off + (size_t)E * sizeof(int));
    uint32*   bbuf     = (uint32*)(w + off);   off = alignup(off + (size_t)nbuckets * bcap * sizeof(uint32));
    uint32*   A        = (uint32*)(w + off);   off = alignup(off + (size_t)N * HID * sizeof(ushort16));
    uint32*   B        = (uint32*)(w + off);   off = alignup(off + (size_t)N * HID * sizeof(ushort16));

    const int nbN = (N + TPB - 1) / TPB;   // 391
    const int nbE = (E + TPB - 1) / TPB;
    const int gemmBlocks = (N + 63) / 64;

    detect_i64_kernel<<<1, TPB, 0, stream>>>((const uint32*)ei, 256, flag);

    if (bucketed) {
        hipMemsetAsync(bcur, 0, MAXBK * sizeof(int), stream);
        const int PB = (E + PT_TILE - 1) / PT_TILE;     // 782 partition blocks
        // mega1: partition (blocks 0..PB-1) runs CONCURRENTLY with raw layer-1 GEMM
        mega1_kernel<<<PB + gemmBlocks, TPB, 0, stream>>>(
            ei, E, flag, nbuckets, bcap, bcur, bbuf, x, W1, (ushort16*)A, N, PB);
        bucket_base_kernel<<<1, 512, 0, stream>>>(bcur, bbase, nbuckets, bcap);
        bucket_count2_kernel<<<nbuckets, TPB, 0, stream>>>(bbuf, bcur, bbase, counts, dis, row_ptr, N, bcap);
        bucket_fill_kernel<<<nbuckets, TPB, 0, stream>>>(bbuf, bcur, row_ptr, csr, N, bcap);
    } else {
        hipMemsetAsync(counts, 0, (size_t)(N + MAXBK) * sizeof(int), stream);
        hist_kernel<<<nbE, TPB, 0, stream>>>(ei, E, flag, counts);
        dis_kernel<<<nbN, TPB, 0, stream>>>(counts, dis, N);
        scan_block_kernel<<<nbN, TPB, 0, stream>>>(counts, row_ptr, partials, N);
        scan_partials_kernel<<<1, 512, 0, stream>>>(partials, nbN);
        add_offsets_kernel<<<nbN, TPB, 0, stream>>>(row_ptr, partials, cursor, N);
        fill_kernel<<<nbE, TPB, 0, stream>>>(ei, E, flag, cursor, csr);
        // raw layer-1 GEMM (dis applied inside agg128)
        gemm_mfma_kernel<HID, false, false><<<gemmBlocks, TPB, 0, stream>>>(x, W1, dis, (ushort16*)A, N);
    }

    // ---- layer 1 aggregation: h1 = relu(dis*(dis*h[d] + sum dis[s]h[s]) + b1)
    agg128_kernel<<<(N + 3) / 4, TPB, 0, stream>>>(A, csr, row_ptr, counts, dis, b1, B, N);

    // ---- layer 2: hs2 = bf16((h1@W2)*dis) ; out = 0.1+0.8*sigmoid(dis*(hs2[d]+sum hs2[s])+b2)
    gemm_mfma_kernel<OUTF, true, true><<<gemmBlocks, TPB, 0, stream>>>(B, W2, dis, (ushort16*)A, N);
    agg64_kernel<<<(N + 3) / 4, TPB, 0, stream>>>(A, csr, row_ptr, counts, dis, b2, (float*)d_out, N);
}